// Round 6
// baseline (3623.536 us; speedup 1.0000x reference)
//
#include <hip/hip_runtime.h>
#include <cstdio>

typedef __attribute__((ext_vector_type(8))) short short8_t;
typedef __attribute__((ext_vector_type(8))) unsigned short ushort8_t;
typedef __attribute__((ext_vector_type(4))) unsigned short us4;
typedef __attribute__((ext_vector_type(4))) float f32x4;

__device__ __forceinline__ unsigned short f2bf(float f) {
  unsigned u = __float_as_uint(f);
  u = u + 0x7FFFu + ((u >> 16) & 1u);
  return (unsigned short)(u >> 16);
}
__device__ __forceinline__ float bf2f(unsigned short h) {
  return __uint_as_float((unsigned)h << 16);
}
__device__ __forceinline__ float lrelu(float x) { return x > 0.f ? x : 0.2f * x; }

// ---------------- weight pack ----------------
// Pack all 6 weights into MFMA-fragment order so the GEMM inner loop reads LDS at
// base + lane*16 (conflict-free linear). Element W[k][n]:
//   col n -> nt = n>>4, l16 = n&15 ; k -> ks = k>>5, quad = (k>>3)&3, j = k&7
//   WF[which][ ((nt*8+ks)*64 + quad*16 + l16)*8 + j ]  (lane = quad*16+l16)
__global__ void k_pack_w6(const float* __restrict__ W0, const float* __restrict__ W1,
                          const float* __restrict__ W2, const float* __restrict__ W3,
                          const float* __restrict__ W4, const float* __restrict__ W5,
                          unsigned short* __restrict__ WF) {
  int which = blockIdx.x >> 8, k = blockIdx.x & 255, n = threadIdx.x;
  const float* W = which == 0 ? W0 : which == 1 ? W1 : which == 2 ? W2
                 : which == 3 ? W3 : which == 4 ? W4 : W5;
  int nt = n >> 4, l16 = n & 15;
  int ks = k >> 5, quad = (k >> 3) & 3, j = k & 7;
  size_t idx = ((size_t)which << 16) + (size_t)(((nt * 8 + ks) * 64 + quad * 16 + l16) * 8 + j);
  WF[idx] = f2bf(W[k * 256 + n]);
}

// ---------------- CSR build (fused over the 3 index arrays) ----------------

__global__ void k_count3(const int* __restrict__ hg_node, const int* __restrict__ hg_edge,
                         const int* __restrict__ oe_obj, int* __restrict__ cn,
                         int* __restrict__ ce, int* __restrict__ co, int nE2, int nE1) {
  int e = blockIdx.x * blockDim.x + threadIdx.x;
  if (e < nE2) {
    atomicAdd(&cn[hg_node[e]], 1);
    atomicAdd(&ce[hg_edge[e]], 1);
  }
  if (e < nE1) atomicAdd(&co[oe_obj[e]], 1);
}

// fill CSR-ordered VALUE arrays directly (kills the perm->index hop in gathers):
//   PE[node pos]  = (e0, hg_edge[e0])  (int2, one 8B scatter)
//   NDe[edge pos] = hg_node[e]
//   EVo[obj pos]  = oe_ev[e]
__global__ void k_fill3(const int* __restrict__ hg_node, const int* __restrict__ hg_edge,
                        const int* __restrict__ oe_ev, const int* __restrict__ oe_obj,
                        const int* __restrict__ NS, const int* __restrict__ ES,
                        const int* __restrict__ OS, int* __restrict__ curn,
                        int* __restrict__ cure, int* __restrict__ curo,
                        int2* __restrict__ PE, int* __restrict__ NDe, int* __restrict__ EVo,
                        int nE2, int nE1) {
  int e = blockIdx.x * blockDim.x + threadIdx.x;
  if (e < nE2) {
    int sn = hg_node[e], se = hg_edge[e];
    int pn = NS[sn] + atomicAdd(&curn[sn], 1);
    PE[pn] = make_int2(e, se);
    int pe = ES[se] + atomicAdd(&cure[se], 1);
    NDe[pe] = sn;
  }
  if (e < nE1) {
    int so = oe_obj[e];
    int po = OS[so] + atomicAdd(&curo[so], 1);
    EVo[po] = oe_ev[e];
  }
}

// three single-block exclusive scans running concurrently (block b -> job b).
// starts[0..n] (starts[n] = total). block = 1024.
__global__ __launch_bounds__(1024) void k_scan3(const int* __restrict__ c0, int* __restrict__ s0,
                                                int n0, const int* __restrict__ c1,
                                                int* __restrict__ s1, int n1,
                                                const int* __restrict__ c2, int* __restrict__ s2,
                                                int n2) {
  const int* cnt;
  int* starts;
  int n;
  if (blockIdx.x == 0) { cnt = c0; starts = s0; n = n0; }
  else if (blockIdx.x == 1) { cnt = c1; starts = s1; n = n1; }
  else { cnt = c2; starts = s2; n = n2; }
  __shared__ int wsum[16];
  int tid = threadIdx.x, lane = tid & 63, w = tid >> 6;
  int carry = 0;
  for (int base = 0; base < n; base += 4096) {
    int i0 = base + tid * 4;
    int4 c = make_int4(0, 0, 0, 0);
    if (i0 + 3 < n) c = *(const int4*)(cnt + i0);
    else {
      if (i0 < n) c.x = cnt[i0];
      if (i0 + 1 < n) c.y = cnt[i0 + 1];
      if (i0 + 2 < n) c.z = cnt[i0 + 2];
      if (i0 + 3 < n) c.w = cnt[i0 + 3];
    }
    int tsum = c.x + c.y + c.z + c.w;
    int inc = tsum;
    for (int o = 1; o < 64; o <<= 1) {
      int v = __shfl_up(inc, o);
      if (lane >= o) inc += v;
    }
    if (lane == 63) wsum[w] = inc;
    __syncthreads();
    int woff = 0;
    for (int k = 0; k < w; k++) woff += wsum[k];
    int excl = carry + woff + inc - tsum;
    if (i0 < n) starts[i0] = excl;
    if (i0 + 1 < n) starts[i0 + 1] = excl + c.x;
    if (i0 + 2 < n) starts[i0 + 2] = excl + c.x + c.y;
    if (i0 + 3 < n) starts[i0 + 3] = excl + c.x + c.y + c.z;
    int total = 0;
    for (int k = 0; k < 16; k++) total += wsum[k];
    carry += total;
    __syncthreads();
  }
  if (tid == 0) starts[n] = carry;
}

// ---------------- persistent B-resident GEMM (+bias+lrelu+skip+LN) --------------------
// WF (131 KB, fragment-ordered) is staged into LDS ONCE per block (1 block/CU by LDS).
// Block = 1024 threads = 16 waves = 4 waves/EU; __launch_bounds__(1024, 4) sets the
// VGPR budget to 128 so the ~115-reg live set (acc 64 + af 32 + addr) does NOT spill
// (round-4's single-arg bounds capped at 64 VGPR -> scratch spill -> 1.28 GB HBM/dispatch).
// Each wave owns independent 16-row tiles in a grid-stride loop: no barriers, no LDS
// re-staging, conflict-free lane*16 ds_reads. Accumulation order identical -> same numerics.
template <int HAS_SKIP, int A_F32>
__global__ __launch_bounds__(1024, 4) void k_gemm_ln(const void* __restrict__ Av,
                                                     const unsigned short* __restrict__ WF,
                                                     const float* __restrict__ bias,
                                                     const float* __restrict__ gamma,
                                                     const float* __restrict__ beta,
                                                     const unsigned short* skip,
                                                     unsigned short* outb, int rows,
                                                     int nTiles) {
  __shared__ unsigned short Bs[65536];  // 131072 B: full 256x256 bf16 B, fragment order
  int tid = threadIdx.x;
#pragma unroll
  for (int i = 0; i < 8; i++)
    *(ushort8_t*)&Bs[(i * 1024 + tid) * 8] = *(const ushort8_t*)&WF[(size_t)(i * 1024 + tid) * 8];
  __syncthreads();
  int wave = tid >> 6, lane = tid & 63;
  int quad = lane >> 4, l16 = lane & 15;

  for (int t = blockIdx.x * 16 + wave; t < nTiles; t += gridDim.x * 16) {
    size_t row0 = (size_t)t * 16;
    size_t arow = row0 + l16;
    short8_t af[8];
    if (A_F32) {
      bool inr = arow < (size_t)rows;
      const float4* ap = (const float4*)((const float*)Av + arow * 256);
#pragma unroll
      for (int ks = 0; ks < 8; ks++) {
        float4 f0 = make_float4(0.f, 0.f, 0.f, 0.f), f1 = f0;
        if (inr) {
          f0 = ap[ks * 8 + quad * 2];
          f1 = ap[ks * 8 + quad * 2 + 1];
        }
        ushort8_t a;
        a[0] = f2bf(f0.x); a[1] = f2bf(f0.y); a[2] = f2bf(f0.z); a[3] = f2bf(f0.w);
        a[4] = f2bf(f1.x); a[5] = f2bf(f1.y); a[6] = f2bf(f1.z); a[7] = f2bf(f1.w);
        af[ks] = (short8_t)a;
      }
    } else {
      const ushort8_t* ap = (const ushort8_t*)((const unsigned short*)Av + arow * 256);
#pragma unroll
      for (int ks = 0; ks < 8; ks++) af[ks] = (short8_t)ap[ks * 4 + quad];
    }

    f32x4 acc[16];
#pragma unroll
    for (int i = 0; i < 16; i++) acc[i] = (f32x4){0.f, 0.f, 0.f, 0.f};
#pragma unroll
    for (int ks = 0; ks < 8; ks++) {
#pragma unroll
      for (int nt = 0; nt < 16; nt++) {
        short8_t bf = *(const short8_t*)&Bs[((nt * 8 + ks) * 64 + lane) * 8];
        acc[nt] = __builtin_amdgcn_mfma_f32_16x16x32_bf16(af[ks], bf, acc[nt], 0, 0, 0);
      }
    }

    size_t rbase = row0 + quad * 4;
#pragma unroll
    for (int nt = 0; nt < 16; nt++) {
      int col = nt * 16 + l16;
      float bv = bias[col];
#pragma unroll
      for (int r = 0; r < 4; r++) {
        float x = lrelu(acc[nt][r] + bv);
        if (HAS_SKIP) {
          if (rbase + r < (size_t)rows) x += bf2f(skip[(rbase + r) * 256 + col]);
        }
        acc[nt][r] = x;
      }
    }
    float s[4] = {0, 0, 0, 0}, q[4] = {0, 0, 0, 0};
#pragma unroll
    for (int nt = 0; nt < 16; nt++)
#pragma unroll
      for (int r = 0; r < 4; r++) {
        float x = acc[nt][r];
        s[r] += x;
        q[r] += x * x;
      }
#pragma unroll
    for (int o = 1; o < 16; o <<= 1)
#pragma unroll
      for (int r = 0; r < 4; r++) {
        s[r] += __shfl_xor(s[r], o);
        q[r] += __shfl_xor(q[r], o);
      }
    float mr[4], rs[4];
#pragma unroll
    for (int r = 0; r < 4; r++) {
      float m = s[r] * (1.f / 256.f);
      float v = q[r] * (1.f / 256.f) - m * m;
      mr[r] = m;
      rs[r] = rsqrtf(v + 1e-5f);
    }
#pragma unroll
    for (int nt = 0; nt < 16; nt++) {
      int col = nt * 16 + l16;
      float g = gamma[col], bb = beta[col];
#pragma unroll
      for (int r = 0; r < 4; r++) {
        if (rbase + r < (size_t)rows) {
          float y = (acc[nt][r] - mr[r]) * rs[r] * g + bb;
          outb[(rbase + r) * 256 + col] = f2bf(y);
        }
      }
    }
  }
}

// ---------------- persistent B-resident GEMM for HGNN: XW (bf16, in-place) + s1 -------
__global__ __launch_bounds__(1024, 4) void k_gemm_xw(unsigned short* A,
                                                     const unsigned short* __restrict__ WF,
                                                     const float* __restrict__ a1,
                                                     float* __restrict__ s1, int rows,
                                                     int nTiles) {
  __shared__ unsigned short Bs[65536];
  int tid = threadIdx.x;
#pragma unroll
  for (int i = 0; i < 8; i++)
    *(ushort8_t*)&Bs[(i * 1024 + tid) * 8] = *(const ushort8_t*)&WF[(size_t)(i * 1024 + tid) * 8];
  __syncthreads();
  int wave = tid >> 6, lane = tid & 63;
  int quad = lane >> 4, l16 = lane & 15;

  for (int t = blockIdx.x * 16 + wave; t < nTiles; t += gridDim.x * 16) {
    size_t row0 = (size_t)t * 16;
    size_t arow = row0 + l16;
    short8_t af[8];
    const ushort8_t* ap = (const ushort8_t*)(A + arow * 256);
#pragma unroll
    for (int ks = 0; ks < 8; ks++) af[ks] = (short8_t)ap[ks * 4 + quad];

    f32x4 acc[16];
#pragma unroll
    for (int i = 0; i < 16; i++) acc[i] = (f32x4){0.f, 0.f, 0.f, 0.f};
#pragma unroll
    for (int ks = 0; ks < 8; ks++) {
#pragma unroll
      for (int nt = 0; nt < 16; nt++) {
        short8_t bf = *(const short8_t*)&Bs[((nt * 8 + ks) * 64 + lane) * 8];
        acc[nt] = __builtin_amdgcn_mfma_f32_16x16x32_bf16(af[ks], bf, acc[nt], 0, 0, 0);
      }
    }

    size_t rbase = row0 + quad * 4;
    float s[4] = {0, 0, 0, 0};
#pragma unroll
    for (int nt = 0; nt < 16; nt++) {
      float av = a1[nt * 16 + l16];
#pragma unroll
      for (int r = 0; r < 4; r++) s[r] += acc[nt][r] * av;
    }
#pragma unroll
    for (int o = 1; o < 16; o <<= 1)
#pragma unroll
      for (int r = 0; r < 4; r++) s[r] += __shfl_xor(s[r], o);
#pragma unroll
    for (int nt = 0; nt < 16; nt++) {
      int col = nt * 16 + l16;
#pragma unroll
      for (int r = 0; r < 4; r++)
        if (rbase + r < (size_t)rows) A[(rbase + r) * 256 + col] = f2bf(acc[nt][r]);
    }
    if (l16 == 0) {
#pragma unroll
      for (int r = 0; r < 4; r++)
        if (rbase + r < (size_t)rows) s1[rbase + r] = s[r];
    }
  }
}

// ---------------- CSR gathers ----------------
// Pass 1 loads CSR-ordered metadata lane-parallel (single hop). Accumulate pass
// broadcasts via __shfl and issues row loads in batches of 8 (MLP). EF is stored
// bf16 (halves the dominant random-row stream); s2 stays computed from the f32
// accumulator so attention weights are bit-identical to the f32-EF version.

// per hyperedge r (one wave): ef[r] = mean of XW[node] rows (bf16 out); s2[r] = ef_f32·a2
__global__ __launch_bounds__(256) void k_edge_gather(const unsigned short* __restrict__ XW,
                                                     const int* __restrict__ ES,
                                                     const int* __restrict__ NDe,
                                                     const float* __restrict__ a2,
                                                     unsigned short* __restrict__ EF,
                                                     float* __restrict__ s2, int nEdges) {
  int wave = threadIdx.x >> 6, lane = threadIdx.x & 63;
  int r = blockIdx.x * 4 + wave;
  if (r >= nEdges) return;
  int s = ES[r], e = ES[r + 1];
  int cnt = e - s;
  float4 acc = make_float4(0.f, 0.f, 0.f, 0.f);
  if (cnt <= 64) {
    int myn = 0;
    if (lane < cnt) myn = NDe[s + lane];
    for (int base = 0; base < cnt; base += 8) {
      us4 u[8];
      float f[8];
#pragma unroll
      for (int t = 0; t < 8; t++) {
        int j2 = base + t;  // <= 63 always (cnt <= 64)
        int n1 = __shfl(myn, j2);
        u[t] = ((const us4*)(XW + (size_t)n1 * 256))[lane];
        f[t] = (j2 < cnt) ? 1.f : 0.f;
      }
#pragma unroll
      for (int t = 0; t < 8; t++) {
        acc.x += f[t] * bf2f(u[t].x);
        acc.y += f[t] * bf2f(u[t].y);
        acc.z += f[t] * bf2f(u[t].z);
        acc.w += f[t] * bf2f(u[t].w);
      }
    }
  } else {
    for (int j = s; j < e; j++) {
      int n = NDe[j];
      us4 u = ((const us4*)(XW + (size_t)n * 256))[lane];
      acc.x += bf2f(u.x); acc.y += bf2f(u.y);
      acc.z += bf2f(u.z); acc.w += bf2f(u.w);
    }
  }
  float inv = 1.f / (float)(cnt > 1 ? cnt : 1);
  acc.x *= inv; acc.y *= inv; acc.z *= inv; acc.w *= inv;
  us4 ub = {f2bf(acc.x), f2bf(acc.y), f2bf(acc.z), f2bf(acc.w)};
  ((us4*)(EF + (size_t)r * 256))[lane] = ub;
  float4 a = ((const float4*)a2)[lane];
  float d = acc.x * a.x + acc.y * a.y + acc.z * a.z + acc.w * a.w;
  for (int o = 32; o; o >>= 1) d += __shfl_xor(d, o);
  if (lane == 0) s2[r] = d;
}

// per node n (one wave): in-wave softmax over incidences + weighted EF gather + lrelu
template <int WRITE_ATTN>
__global__ __launch_bounds__(256) void k_node_gather(const int* __restrict__ NS,
                                                     const int2* __restrict__ PE,
                                                     const float* __restrict__ s1,
                                                     const float* __restrict__ s2,
                                                     const unsigned short* __restrict__ EF,
                                                     unsigned short* outb, float* outf,
                                                     float* attn_out, int nNodes) {
  int wave = threadIdx.x >> 6, lane = threadIdx.x & 63;
  int n = blockIdx.x * 4 + wave;
  if (n >= nNodes) return;
  int s = NS[n], e = NS[n + 1];
  int cnt = e - s;
  float s1n = s1[n];
  float4 acc = make_float4(0.f, 0.f, 0.f, 0.f);
  if (cnt <= 64) {
    int mye0 = 0, myed = 0;
    float myscore = -3.4e38f;
    bool act = lane < cnt;
    if (act) {
      int2 pe = PE[s + lane];
      mye0 = pe.x;
      myed = pe.y;
      myscore = lrelu(s1n + s2[myed]);
    }
    float mymax = myscore;
    for (int o = 32; o; o >>= 1) mymax = fmaxf(mymax, __shfl_xor(mymax, o));
    float myexp = act ? __expf(myscore - mymax) : 0.f;
    float mysum = myexp;
    for (int o = 32; o; o >>= 1) mysum += __shfl_xor(mysum, o);
    float zinv = 1.f / fmaxf(mysum, 1e-9f);
    float myw = myexp * zinv;  // == 0 for inactive lanes
    if (WRITE_ATTN && act) attn_out[mye0] = myw;
    for (int base = 0; base < cnt; base += 8) {
      us4 v[8];
      float w[8];
#pragma unroll
      for (int t = 0; t < 8; t++) {
        int j2 = base + t;  // <= 63 always
        int ed = __shfl(myed, j2);
        w[t] = __shfl(myw, j2);
        v[t] = ((const us4*)(EF + (size_t)ed * 256))[lane];
      }
#pragma unroll
      for (int t = 0; t < 8; t++) {
        acc.x += w[t] * bf2f(v[t].x);
        acc.y += w[t] * bf2f(v[t].y);
        acc.z += w[t] * bf2f(v[t].z);
        acc.w += w[t] * bf2f(v[t].w);
      }
    }
  } else {
    float mymax = -3.4e38f;
    for (int j = s + lane; j < e; j += 64) {
      mymax = fmaxf(mymax, lrelu(s1n + s2[PE[j].y]));
    }
    for (int o = 32; o; o >>= 1) mymax = fmaxf(mymax, __shfl_xor(mymax, o));
    float mysum = 0.f;
    for (int j = s + lane; j < e; j += 64) {
      mysum += __expf(lrelu(s1n + s2[PE[j].y]) - mymax);
    }
    for (int o = 32; o; o >>= 1) mysum += __shfl_xor(mysum, o);
    float zinv = 1.f / fmaxf(mysum, 1e-9f);
    for (int j = s; j < e; j++) {
      int2 pe = PE[j];
      float w = __expf(lrelu(s1n + s2[pe.y]) - mymax) * zinv;
      if (WRITE_ATTN) {
        if (lane == 0) attn_out[pe.x] = w;
      }
      us4 v = ((const us4*)(EF + (size_t)pe.y * 256))[lane];
      acc.x += w * bf2f(v.x); acc.y += w * bf2f(v.y);
      acc.z += w * bf2f(v.z); acc.w += w * bf2f(v.w);
    }
  }
  acc.x = lrelu(acc.x); acc.y = lrelu(acc.y);
  acc.z = lrelu(acc.z); acc.w = lrelu(acc.w);
  if (outb) {
    us4 u = {f2bf(acc.x), f2bf(acc.y), f2bf(acc.z), f2bf(acc.w)};
    ((us4*)(outb + (size_t)n * 256))[lane] = u;
  } else {
    ((float4*)(outf + (size_t)n * 256))[lane] = acc;
  }
}

// per object o (one wave): msg[o] = sum of ev rows (bf16 in, bf16 out)
__global__ __launch_bounds__(256) void k_obj_gather(const unsigned short* __restrict__ EVB,
                                                    const int* __restrict__ OS,
                                                    const int* __restrict__ EVo,
                                                    unsigned short* __restrict__ outb,
                                                    int nObj) {
  int wave = threadIdx.x >> 6, lane = threadIdx.x & 63;
  int o = blockIdx.x * 4 + wave;
  if (o >= nObj) return;
  int s = OS[o], e = OS[o + 1];
  int cnt = e - s;
  float4 acc = make_float4(0.f, 0.f, 0.f, 0.f);
  if (cnt <= 64) {
    int myev = 0;
    if (lane < cnt) myev = EVo[s + lane];
    for (int base = 0; base < cnt; base += 8) {
      us4 u[8];
      float f[8];
#pragma unroll
      for (int t = 0; t < 8; t++) {
        int j2 = base + t;  // <= 63 always
        int v1 = __shfl(myev, j2);
        u[t] = ((const us4*)(EVB + (size_t)v1 * 256))[lane];
        f[t] = (j2 < cnt) ? 1.f : 0.f;
      }
#pragma unroll
      for (int t = 0; t < 8; t++) {
        acc.x += f[t] * bf2f(u[t].x);
        acc.y += f[t] * bf2f(u[t].y);
        acc.z += f[t] * bf2f(u[t].z);
        acc.w += f[t] * bf2f(u[t].w);
      }
    }
  } else {
    for (int j = s; j < e; j++) {
      int ev = EVo[j];
      us4 u = ((const us4*)(EVB + (size_t)ev * 256))[lane];
      acc.x += bf2f(u.x); acc.y += bf2f(u.y);
      acc.z += bf2f(u.z); acc.w += bf2f(u.w);
    }
  }
  us4 u = {f2bf(acc.x), f2bf(acc.y), f2bf(acc.z), f2bf(acc.w)};
  ((us4*)(outb + (size_t)o * 256))[lane] = u;
}

// ---------------- driver ----------------

extern "C" void kernel_launch(void* const* d_in, const int* in_sizes, int n_in,
                              void* d_out, int out_size, void* d_ws, size_t ws_size,
                              hipStream_t stream) {
  (void)n_in; (void)out_size;
  const float* object_X = (const float*)d_in[0];
  const float* event_X = (const float*)d_in[1];
  const float* Wo = (const float*)d_in[2];   const float* bo = (const float*)d_in[3];
  const float* go = (const float*)d_in[4];   const float* bon = (const float*)d_in[5];
  const float* We = (const float*)d_in[6];   const float* be = (const float*)d_in[7];
  const float* ge = (const float*)d_in[8];   const float* ben = (const float*)d_in[9];
  const float* Wu = (const float*)d_in[10];  const float* bu = (const float*)d_in[11];
  const float* Wl = (const float*)d_in[12];  const float* bl = (const float*)d_in[13];
  const float* g1 = (const float*)d_in[14];  const float* b1 = (const float*)d_in[15];
  const float* g2 = (const float*)d_in[16];  const float* b2 = (const float*)d_in[17];
  const float* Wh1 = (const float*)d_in[18]; const float* ah1 = (const float*)d_in[19];
  const float* Wh2 = (const float*)d_in[20]; const float* ah2 = (const float*)d_in[21];
  const int* oe_ev = (const int*)d_in[22];
  const int* oe_obj = (const int*)d_in[23];
  const int* hg_node = (const int*)d_in[24];
  const int* hg_edge = (const int*)d_in[25];

  const int N_OBJ = in_sizes[0] / 256;
  const int N_EV = in_sizes[1] / 256;
  const int E1 = in_sizes[22];
  const int E2 = in_sizes[24];
  const int NN = N_EV + N_OBJ;
  const int MEV = ((N_EV + 63) / 64) * 64;
  const int MOB = ((N_OBJ + 63) / 64) * 64;
  const int MX = ((NN + 63) / 64) * 64;
  const int EMX = E2 > E1 ? E2 : E1;

  char* p = (char*)d_ws;
  auto take = [&](size_t bytes) {
    char* r = p;
    p += (bytes + 255) & ~(size_t)255;
    return r;
  };
  unsigned short* WF = (unsigned short*)take((size_t)6 * 65536 * 2);  // 0.79 MB frag-packed
  unsigned short* XBF = (unsigned short*)take((size_t)MX * 256 * 2);  // 76.8 MB  X / XW / h
  unsigned short* SB = (unsigned short*)take((size_t)MOB * 256 * 2);  // 51.2 MB staging
  unsigned short* EF = SB;  // alias (bf16): SB dead once the obj2 GEMM has consumed it
  float* S1 = (float*)take((size_t)NN * 4);
  float* S2 = (float*)take((size_t)N_EV * 4);
  int* NS = (int*)take((size_t)(NN + 1) * 4);      // node CSR starts
  int* ES = (int*)take((size_t)(N_EV + 1) * 4);    // edge CSR starts
  int* OS = (int*)take((size_t)(N_OBJ + 1) * 4);   // obj CSR starts
  int* CNTn = (int*)take((size_t)NN * 4);          // counts, reused as fill cursors
  int* CNTe = (int*)take((size_t)N_EV * 4);
  int* CNTo = (int*)take((size_t)N_OBJ * 4);
  int2* PEn = (int2*)take((size_t)E2 * 8);         // (e0, hg_edge[e0]) in node-CSR order
  int* NDe = (int*)take((size_t)E2 * 4);           // hg_node values in edge-CSR order
  int* EVo = (int*)take((size_t)E1 * 4);           // oe_ev values in obj-CSR order
  size_t need = (size_t)(p - (char*)d_ws);
  if (need > ws_size)
    fprintf(stderr, "[kernel_launch] WS OVERFLOW: need=%zu have=%zu\n", need, ws_size);

  float* out = (float*)d_out;
  // obj skip (bf16, 51.2 MB) lives in d_out — dead region until layer-2 outputs
  unsigned short* OBJB = (unsigned short*)d_out;

  // --- weights -> bf16 fragment-packed (one fused launch; slots: We,Wo,Wu,Wl,Wh1,Wh2) ---
  k_pack_w6<<<6 * 256, 256, 0, stream>>>(We, Wo, Wu, Wl, Wh1, Wh2, WF);

  if (MX > NN)
    hipMemsetAsync(XBF + (size_t)NN * 256, 0, (size_t)(MX - NN) * 512, stream);

  // --- CSR builds (node/E2, edge/E2, obj/E1), fused ---
  size_t cnt_span = (size_t)((char*)PEn - (char*)CNTn);  // CNTn..CNTo contiguous
  hipMemsetAsync(CNTn, 0, cnt_span, stream);
  k_count3<<<(EMX + 255) / 256, 256, 0, stream>>>(hg_node, hg_edge, oe_obj, CNTn, CNTe, CNTo,
                                                  E2, E1);
  k_scan3<<<3, 1024, 0, stream>>>(CNTn, NS, NN, CNTe, ES, N_EV, CNTo, OS, N_OBJ);
  hipMemsetAsync(CNTn, 0, cnt_span, stream);
  k_fill3<<<(EMX + 255) / 256, 256, 0, stream>>>(hg_node, hg_edge, oe_ev, oe_obj, NS, ES, OS,
                                                 CNTn, CNTe, CNTo, PEn, NDe, EVo, E2, E1);

  // --- ev = LN(lrelu(event_X@We + be)) -> XBF rows [0,N_EV) bf16 (f32 A fused) ---
  k_gemm_ln<0, 1><<<256, 1024, 0, stream>>>(event_X, WF + 0 * 65536, be, ge, ben, nullptr,
                                            XBF, N_EV, MEV / 16);
  // --- obj = LN(lrelu(object_X@Wo + bo)) -> OBJB bf16 (in d_out) ---
  k_gemm_ln<0, 1><<<256, 1024, 0, stream>>>(object_X, WF + 1 * 65536, bo, go, bon, nullptr,
                                            OBJB, N_OBJ, MOB / 16);
  // --- msg (CSR gather, bf16) -> SB; obj1 = LN(lrelu(msg@Wu+bu)+obj) -> SB ---
  k_obj_gather<<<(N_OBJ + 3) / 4, 256, 0, stream>>>(XBF, OS, EVo, SB, N_OBJ);
  k_gemm_ln<1, 0><<<256, 1024, 0, stream>>>(SB, WF + 2 * 65536, bu, g1, b1, OBJB, SB, N_OBJ,
                                            MOB / 16);
  // --- obj2 = LN(lrelu(obj1@Wl+bl)+obj1) -> XBF rows [N_EV,NN) bf16 ---
  k_gemm_ln<1, 0><<<256, 1024, 0, stream>>>(SB, WF + 3 * 65536, bl, g2, b2, SB,
                                            XBF + (size_t)N_EV * 256, N_OBJ, MOB / 16);

  // --- HGNN layer 1: h -> XBF bf16 (SB now dead; EF aliases it) ---
  k_gemm_xw<<<256, 1024, 0, stream>>>(XBF, WF + 4 * 65536, ah1, S1, NN, MX / 16);
  k_edge_gather<<<(N_EV + 3) / 4, 256, 0, stream>>>(XBF, ES, NDe, ah1 + 256, EF, S2, N_EV);
  k_node_gather<0><<<(NN + 3) / 4, 256, 0, stream>>>(NS, PEn, S1, S2, EF, XBF, nullptr,
                                                     nullptr, NN);
  // --- HGNN layer 2: h f32 + attn -> d_out ---
  k_gemm_xw<<<256, 1024, 0, stream>>>(XBF, WF + 5 * 65536, ah2, S1, NN, MX / 16);
  k_edge_gather<<<(N_EV + 3) / 4, 256, 0, stream>>>(XBF, ES, NDe, ah2 + 256, EF, S2, N_EV);
  k_node_gather<1><<<(NN + 3) / 4, 256, 0, stream>>>(NS, PEn, S1, S2, EF, nullptr, out,
                                                     out + (size_t)NN * 256, NN);
}

// Round 7
// 3620.869 us; speedup vs baseline: 1.0007x; 1.0007x over previous
//
#include <hip/hip_runtime.h>
#include <cstdio>

typedef __attribute__((ext_vector_type(8))) short short8_t;
typedef __attribute__((ext_vector_type(8))) unsigned short ushort8_t;
typedef __attribute__((ext_vector_type(4))) unsigned short us4;
typedef __attribute__((ext_vector_type(4))) float f32x4;

__device__ __forceinline__ unsigned short f2bf(float f) {
  unsigned u = __float_as_uint(f);
  u = u + 0x7FFFu + ((u >> 16) & 1u);
  return (unsigned short)(u >> 16);
}
__device__ __forceinline__ float bf2f(unsigned short h) {
  return __uint_as_float((unsigned)h << 16);
}
__device__ __forceinline__ float lrelu(float x) { return x > 0.f ? x : 0.2f * x; }

// ---------------- weight pack ----------------
// Pack all 6 weights into MFMA-fragment order so the GEMM inner loop reads LDS at
// base + lane*16 (conflict-free linear). Element W[k][n]:
//   col n -> nt = n>>4, l16 = n&15 ; k -> ks = k>>5, quad = (k>>3)&3, j = k&7
//   WF[which][ ((nt*8+ks)*64 + quad*16 + l16)*8 + j ]  (lane = quad*16+l16)
__global__ void k_pack_w6(const float* __restrict__ W0, const float* __restrict__ W1,
                          const float* __restrict__ W2, const float* __restrict__ W3,
                          const float* __restrict__ W4, const float* __restrict__ W5,
                          unsigned short* __restrict__ WF) {
  int which = blockIdx.x >> 8, k = blockIdx.x & 255, n = threadIdx.x;
  const float* W = which == 0 ? W0 : which == 1 ? W1 : which == 2 ? W2
                 : which == 3 ? W3 : which == 4 ? W4 : W5;
  int nt = n >> 4, l16 = n & 15;
  int ks = k >> 5, quad = (k >> 3) & 3, j = k & 7;
  size_t idx = ((size_t)which << 16) + (size_t)(((nt * 8 + ks) * 64 + quad * 16 + l16) * 8 + j);
  WF[idx] = f2bf(W[k * 256 + n]);
}

// ---------------- CSR build (fused over the 3 index arrays) ----------------

__global__ void k_count3(const int* __restrict__ hg_node, const int* __restrict__ hg_edge,
                         const int* __restrict__ oe_obj, int* __restrict__ cn,
                         int* __restrict__ ce, int* __restrict__ co, int nE2, int nE1) {
  int e = blockIdx.x * blockDim.x + threadIdx.x;
  if (e < nE2) {
    atomicAdd(&cn[hg_node[e]], 1);
    atomicAdd(&ce[hg_edge[e]], 1);
  }
  if (e < nE1) atomicAdd(&co[oe_obj[e]], 1);
}

// fill CSR-ordered VALUE arrays directly (kills the perm->index hop in gathers):
//   PE[node pos]  = (e0, hg_edge[e0])  (int2, one 8B scatter)
//   NDe[edge pos] = hg_node[e]
//   EVo[obj pos]  = oe_ev[e]
__global__ void k_fill3(const int* __restrict__ hg_node, const int* __restrict__ hg_edge,
                        const int* __restrict__ oe_ev, const int* __restrict__ oe_obj,
                        const int* __restrict__ NS, const int* __restrict__ ES,
                        const int* __restrict__ OS, int* __restrict__ curn,
                        int* __restrict__ cure, int* __restrict__ curo,
                        int2* __restrict__ PE, int* __restrict__ NDe, int* __restrict__ EVo,
                        int nE2, int nE1) {
  int e = blockIdx.x * blockDim.x + threadIdx.x;
  if (e < nE2) {
    int sn = hg_node[e], se = hg_edge[e];
    int pn = NS[sn] + atomicAdd(&curn[sn], 1);
    PE[pn] = make_int2(e, se);
    int pe = ES[se] + atomicAdd(&cure[se], 1);
    NDe[pe] = sn;
  }
  if (e < nE1) {
    int so = oe_obj[e];
    int po = OS[so] + atomicAdd(&curo[so], 1);
    EVo[po] = oe_ev[e];
  }
}

// three single-block exclusive scans running concurrently (block b -> job b).
// starts[0..n] (starts[n] = total). block = 1024.
__global__ __launch_bounds__(1024) void k_scan3(const int* __restrict__ c0, int* __restrict__ s0,
                                                int n0, const int* __restrict__ c1,
                                                int* __restrict__ s1, int n1,
                                                const int* __restrict__ c2, int* __restrict__ s2,
                                                int n2) {
  const int* cnt;
  int* starts;
  int n;
  if (blockIdx.x == 0) { cnt = c0; starts = s0; n = n0; }
  else if (blockIdx.x == 1) { cnt = c1; starts = s1; n = n1; }
  else { cnt = c2; starts = s2; n = n2; }
  __shared__ int wsum[16];
  int tid = threadIdx.x, lane = tid & 63, w = tid >> 6;
  int carry = 0;
  for (int base = 0; base < n; base += 4096) {
    int i0 = base + tid * 4;
    int4 c = make_int4(0, 0, 0, 0);
    if (i0 + 3 < n) c = *(const int4*)(cnt + i0);
    else {
      if (i0 < n) c.x = cnt[i0];
      if (i0 + 1 < n) c.y = cnt[i0 + 1];
      if (i0 + 2 < n) c.z = cnt[i0 + 2];
      if (i0 + 3 < n) c.w = cnt[i0 + 3];
    }
    int tsum = c.x + c.y + c.z + c.w;
    int inc = tsum;
    for (int o = 1; o < 64; o <<= 1) {
      int v = __shfl_up(inc, o);
      if (lane >= o) inc += v;
    }
    if (lane == 63) wsum[w] = inc;
    __syncthreads();
    int woff = 0;
    for (int k = 0; k < w; k++) woff += wsum[k];
    int excl = carry + woff + inc - tsum;
    if (i0 < n) starts[i0] = excl;
    if (i0 + 1 < n) starts[i0 + 1] = excl + c.x;
    if (i0 + 2 < n) starts[i0 + 2] = excl + c.x + c.y;
    if (i0 + 3 < n) starts[i0 + 3] = excl + c.x + c.y + c.z;
    int total = 0;
    for (int k = 0; k < 16; k++) total += wsum[k];
    carry += total;
    __syncthreads();
  }
  if (tid == 0) starts[n] = carry;
}

// ---------------- persistent B-resident GEMM (+bias+lrelu+skip+LN) --------------------
// WF (131 KB, fragment-ordered) staged into LDS ONCE per block (1 block/CU by LDS).
// Block = 1024 threads = 16 waves = 4 waves/EU. amdgpu_waves_per_eu(4,4) pins the
// allocator's occupancy TARGET to 4 waves/EU -> 128-VGPR budget, so the ~115-reg live
// set does NOT spill. (launch_bounds' 2nd arg is only a MINIMUM waves/EU: rounds 4-5
// still targeted 8 waves/EU -> 64 VGPR -> accumulator spilled to scratch -> 1.28 GB
// HBM/dispatch.) Each wave owns independent 16-row tiles in a grid-stride loop: no
// barriers, no LDS re-staging, conflict-free lane*16 ds_reads. Same math order.
template <int HAS_SKIP, int A_F32>
__global__ __launch_bounds__(1024)
__attribute__((amdgpu_waves_per_eu(4, 4)))
void k_gemm_ln(const void* __restrict__ Av,
               const unsigned short* __restrict__ WF,
               const float* __restrict__ bias,
               const float* __restrict__ gamma,
               const float* __restrict__ beta,
               const unsigned short* skip,
               unsigned short* outb, int rows, int nTiles) {
  __shared__ unsigned short Bs[65536];  // 131072 B: full 256x256 bf16 B, fragment order
  int tid = threadIdx.x;
#pragma unroll
  for (int i = 0; i < 8; i++)
    *(ushort8_t*)&Bs[(i * 1024 + tid) * 8] = *(const ushort8_t*)&WF[(size_t)(i * 1024 + tid) * 8];
  __syncthreads();
  int wave = tid >> 6, lane = tid & 63;
  int quad = lane >> 4, l16 = lane & 15;

  for (int t = blockIdx.x * 16 + wave; t < nTiles; t += gridDim.x * 16) {
    size_t row0 = (size_t)t * 16;
    size_t arow = row0 + l16;
    short8_t af[8];
    if (A_F32) {
      bool inr = arow < (size_t)rows;
      const float4* ap = (const float4*)((const float*)Av + arow * 256);
#pragma unroll
      for (int ks = 0; ks < 8; ks++) {
        float4 f0 = make_float4(0.f, 0.f, 0.f, 0.f), f1 = f0;
        if (inr) {
          f0 = ap[ks * 8 + quad * 2];
          f1 = ap[ks * 8 + quad * 2 + 1];
        }
        ushort8_t a;
        a[0] = f2bf(f0.x); a[1] = f2bf(f0.y); a[2] = f2bf(f0.z); a[3] = f2bf(f0.w);
        a[4] = f2bf(f1.x); a[5] = f2bf(f1.y); a[6] = f2bf(f1.z); a[7] = f2bf(f1.w);
        af[ks] = (short8_t)a;
      }
    } else {
      const ushort8_t* ap = (const ushort8_t*)((const unsigned short*)Av + arow * 256);
#pragma unroll
      for (int ks = 0; ks < 8; ks++) af[ks] = (short8_t)ap[ks * 4 + quad];
    }

    f32x4 acc[16];
#pragma unroll
    for (int i = 0; i < 16; i++) acc[i] = (f32x4){0.f, 0.f, 0.f, 0.f};
#pragma unroll
    for (int ks = 0; ks < 8; ks++) {
#pragma unroll
      for (int nt = 0; nt < 16; nt++) {
        short8_t bf = *(const short8_t*)&Bs[((nt * 8 + ks) * 64 + lane) * 8];
        acc[nt] = __builtin_amdgcn_mfma_f32_16x16x32_bf16(af[ks], bf, acc[nt], 0, 0, 0);
      }
    }

    size_t rbase = row0 + quad * 4;
#pragma unroll
    for (int nt = 0; nt < 16; nt++) {
      int col = nt * 16 + l16;
      float bv = bias[col];
#pragma unroll
      for (int r = 0; r < 4; r++) {
        float x = lrelu(acc[nt][r] + bv);
        if (HAS_SKIP) {
          if (rbase + r < (size_t)rows) x += bf2f(skip[(rbase + r) * 256 + col]);
        }
        acc[nt][r] = x;
      }
    }
    float s[4] = {0, 0, 0, 0}, q[4] = {0, 0, 0, 0};
#pragma unroll
    for (int nt = 0; nt < 16; nt++)
#pragma unroll
      for (int r = 0; r < 4; r++) {
        float x = acc[nt][r];
        s[r] += x;
        q[r] += x * x;
      }
#pragma unroll
    for (int o = 1; o < 16; o <<= 1)
#pragma unroll
      for (int r = 0; r < 4; r++) {
        s[r] += __shfl_xor(s[r], o);
        q[r] += __shfl_xor(q[r], o);
      }
    float mr[4], rs[4];
#pragma unroll
    for (int r = 0; r < 4; r++) {
      float m = s[r] * (1.f / 256.f);
      float v = q[r] * (1.f / 256.f) - m * m;
      mr[r] = m;
      rs[r] = rsqrtf(v + 1e-5f);
    }
#pragma unroll
    for (int nt = 0; nt < 16; nt++) {
      int col = nt * 16 + l16;
      float g = gamma[col], bb = beta[col];
#pragma unroll
      for (int r = 0; r < 4; r++) {
        if (rbase + r < (size_t)rows) {
          float y = (acc[nt][r] - mr[r]) * rs[r] * g + bb;
          outb[(rbase + r) * 256 + col] = f2bf(y);
        }
      }
    }
  }
}

// ---------------- persistent B-resident GEMM for HGNN: XW (bf16, in-place) + s1 -------
__global__ __launch_bounds__(1024)
__attribute__((amdgpu_waves_per_eu(4, 4)))
void k_gemm_xw(unsigned short* A,
               const unsigned short* __restrict__ WF,
               const float* __restrict__ a1,
               float* __restrict__ s1, int rows, int nTiles) {
  __shared__ unsigned short Bs[65536];
  int tid = threadIdx.x;
#pragma unroll
  for (int i = 0; i < 8; i++)
    *(ushort8_t*)&Bs[(i * 1024 + tid) * 8] = *(const ushort8_t*)&WF[(size_t)(i * 1024 + tid) * 8];
  __syncthreads();
  int wave = tid >> 6, lane = tid & 63;
  int quad = lane >> 4, l16 = lane & 15;

  for (int t = blockIdx.x * 16 + wave; t < nTiles; t += gridDim.x * 16) {
    size_t row0 = (size_t)t * 16;
    size_t arow = row0 + l16;
    short8_t af[8];
    const ushort8_t* ap = (const ushort8_t*)(A + arow * 256);
#pragma unroll
    for (int ks = 0; ks < 8; ks++) af[ks] = (short8_t)ap[ks * 4 + quad];

    f32x4 acc[16];
#pragma unroll
    for (int i = 0; i < 16; i++) acc[i] = (f32x4){0.f, 0.f, 0.f, 0.f};
#pragma unroll
    for (int ks = 0; ks < 8; ks++) {
#pragma unroll
      for (int nt = 0; nt < 16; nt++) {
        short8_t bf = *(const short8_t*)&Bs[((nt * 8 + ks) * 64 + lane) * 8];
        acc[nt] = __builtin_amdgcn_mfma_f32_16x16x32_bf16(af[ks], bf, acc[nt], 0, 0, 0);
      }
    }

    size_t rbase = row0 + quad * 4;
    float s[4] = {0, 0, 0, 0};
#pragma unroll
    for (int nt = 0; nt < 16; nt++) {
      float av = a1[nt * 16 + l16];
#pragma unroll
      for (int r = 0; r < 4; r++) s[r] += acc[nt][r] * av;
    }
#pragma unroll
    for (int o = 1; o < 16; o <<= 1)
#pragma unroll
      for (int r = 0; r < 4; r++) s[r] += __shfl_xor(s[r], o);
#pragma unroll
    for (int nt = 0; nt < 16; nt++) {
      int col = nt * 16 + l16;
#pragma unroll
      for (int r = 0; r < 4; r++)
        if (rbase + r < (size_t)rows) A[(rbase + r) * 256 + col] = f2bf(acc[nt][r]);
    }
    if (l16 == 0) {
#pragma unroll
      for (int r = 0; r < 4; r++)
        if (rbase + r < (size_t)rows) s1[rbase + r] = s[r];
    }
  }
}

// ---------------- CSR gathers ----------------
// Pass 1 loads CSR-ordered metadata lane-parallel (single hop). Accumulate pass
// broadcasts via __shfl and issues row loads in batches of 8 (MLP). EF is stored
// bf16 (halves the dominant random-row stream); s2 stays computed from the f32
// accumulator so attention weights are bit-identical to the f32-EF version.

// per hyperedge r (one wave): ef[r] = mean of XW[node] rows (bf16 out); s2[r] = ef_f32·a2
__global__ __launch_bounds__(256) void k_edge_gather(const unsigned short* __restrict__ XW,
                                                     const int* __restrict__ ES,
                                                     const int* __restrict__ NDe,
                                                     const float* __restrict__ a2,
                                                     unsigned short* __restrict__ EF,
                                                     float* __restrict__ s2, int nEdges) {
  int wave = threadIdx.x >> 6, lane = threadIdx.x & 63;
  int r = blockIdx.x * 4 + wave;
  if (r >= nEdges) return;
  int s = ES[r], e = ES[r + 1];
  int cnt = e - s;
  float4 acc = make_float4(0.f, 0.f, 0.f, 0.f);
  if (cnt <= 64) {
    int myn = 0;
    if (lane < cnt) myn = NDe[s + lane];
    for (int base = 0; base < cnt; base += 8) {
      us4 u[8];
      float f[8];
#pragma unroll
      for (int t = 0; t < 8; t++) {
        int j2 = base + t;  // <= 63 always (cnt <= 64)
        int n1 = __shfl(myn, j2);
        u[t] = ((const us4*)(XW + (size_t)n1 * 256))[lane];
        f[t] = (j2 < cnt) ? 1.f : 0.f;
      }
#pragma unroll
      for (int t = 0; t < 8; t++) {
        acc.x += f[t] * bf2f(u[t].x);
        acc.y += f[t] * bf2f(u[t].y);
        acc.z += f[t] * bf2f(u[t].z);
        acc.w += f[t] * bf2f(u[t].w);
      }
    }
  } else {
    for (int j = s; j < e; j++) {
      int n = NDe[j];
      us4 u = ((const us4*)(XW + (size_t)n * 256))[lane];
      acc.x += bf2f(u.x); acc.y += bf2f(u.y);
      acc.z += bf2f(u.z); acc.w += bf2f(u.w);
    }
  }
  float inv = 1.f / (float)(cnt > 1 ? cnt : 1);
  acc.x *= inv; acc.y *= inv; acc.z *= inv; acc.w *= inv;
  us4 ub = {f2bf(acc.x), f2bf(acc.y), f2bf(acc.z), f2bf(acc.w)};
  ((us4*)(EF + (size_t)r * 256))[lane] = ub;
  float4 a = ((const float4*)a2)[lane];
  float d = acc.x * a.x + acc.y * a.y + acc.z * a.z + acc.w * a.w;
  for (int o = 32; o; o >>= 1) d += __shfl_xor(d, o);
  if (lane == 0) s2[r] = d;
}

// per node n (one wave): in-wave softmax over incidences + weighted EF gather + lrelu
template <int WRITE_ATTN>
__global__ __launch_bounds__(256) void k_node_gather(const int* __restrict__ NS,
                                                     const int2* __restrict__ PE,
                                                     const float* __restrict__ s1,
                                                     const float* __restrict__ s2,
                                                     const unsigned short* __restrict__ EF,
                                                     unsigned short* outb, float* outf,
                                                     float* attn_out, int nNodes) {
  int wave = threadIdx.x >> 6, lane = threadIdx.x & 63;
  int n = blockIdx.x * 4 + wave;
  if (n >= nNodes) return;
  int s = NS[n], e = NS[n + 1];
  int cnt = e - s;
  float s1n = s1[n];
  float4 acc = make_float4(0.f, 0.f, 0.f, 0.f);
  if (cnt <= 64) {
    int mye0 = 0, myed = 0;
    float myscore = -3.4e38f;
    bool act = lane < cnt;
    if (act) {
      int2 pe = PE[s + lane];
      mye0 = pe.x;
      myed = pe.y;
      myscore = lrelu(s1n + s2[myed]);
    }
    float mymax = myscore;
    for (int o = 32; o; o >>= 1) mymax = fmaxf(mymax, __shfl_xor(mymax, o));
    float myexp = act ? __expf(myscore - mymax) : 0.f;
    float mysum = myexp;
    for (int o = 32; o; o >>= 1) mysum += __shfl_xor(mysum, o);
    float zinv = 1.f / fmaxf(mysum, 1e-9f);
    float myw = myexp * zinv;  // == 0 for inactive lanes
    if (WRITE_ATTN && act) attn_out[mye0] = myw;
    for (int base = 0; base < cnt; base += 8) {
      us4 v[8];
      float w[8];
#pragma unroll
      for (int t = 0; t < 8; t++) {
        int j2 = base + t;  // <= 63 always
        int ed = __shfl(myed, j2);
        w[t] = __shfl(myw, j2);
        v[t] = ((const us4*)(EF + (size_t)ed * 256))[lane];
      }
#pragma unroll
      for (int t = 0; t < 8; t++) {
        acc.x += w[t] * bf2f(v[t].x);
        acc.y += w[t] * bf2f(v[t].y);
        acc.z += w[t] * bf2f(v[t].z);
        acc.w += w[t] * bf2f(v[t].w);
      }
    }
  } else {
    float mymax = -3.4e38f;
    for (int j = s + lane; j < e; j += 64) {
      mymax = fmaxf(mymax, lrelu(s1n + s2[PE[j].y]));
    }
    for (int o = 32; o; o >>= 1) mymax = fmaxf(mymax, __shfl_xor(mymax, o));
    float mysum = 0.f;
    for (int j = s + lane; j < e; j += 64) {
      mysum += __expf(lrelu(s1n + s2[PE[j].y]) - mymax);
    }
    for (int o = 32; o; o >>= 1) mysum += __shfl_xor(mysum, o);
    float zinv = 1.f / fmaxf(mysum, 1e-9f);
    for (int j = s; j < e; j++) {
      int2 pe = PE[j];
      float w = __expf(lrelu(s1n + s2[pe.y]) - mymax) * zinv;
      if (WRITE_ATTN) {
        if (lane == 0) attn_out[pe.x] = w;
      }
      us4 v = ((const us4*)(EF + (size_t)pe.y * 256))[lane];
      acc.x += w * bf2f(v.x); acc.y += w * bf2f(v.y);
      acc.z += w * bf2f(v.z); acc.w += w * bf2f(v.w);
    }
  }
  acc.x = lrelu(acc.x); acc.y = lrelu(acc.y);
  acc.z = lrelu(acc.z); acc.w = lrelu(acc.w);
  if (outb) {
    us4 u = {f2bf(acc.x), f2bf(acc.y), f2bf(acc.z), f2bf(acc.w)};
    ((us4*)(outb + (size_t)n * 256))[lane] = u;
  } else {
    ((float4*)(outf + (size_t)n * 256))[lane] = acc;
  }
}

// per object o (one wave): msg[o] = sum of ev rows (bf16 in, bf16 out)
__global__ __launch_bounds__(256) void k_obj_gather(const unsigned short* __restrict__ EVB,
                                                    const int* __restrict__ OS,
                                                    const int* __restrict__ EVo,
                                                    unsigned short* __restrict__ outb,
                                                    int nObj) {
  int wave = threadIdx.x >> 6, lane = threadIdx.x & 63;
  int o = blockIdx.x * 4 + wave;
  if (o >= nObj) return;
  int s = OS[o], e = OS[o + 1];
  int cnt = e - s;
  float4 acc = make_float4(0.f, 0.f, 0.f, 0.f);
  if (cnt <= 64) {
    int myev = 0;
    if (lane < cnt) myev = EVo[s + lane];
    for (int base = 0; base < cnt; base += 8) {
      us4 u[8];
      float f[8];
#pragma unroll
      for (int t = 0; t < 8; t++) {
        int j2 = base + t;  // <= 63 always
        int v1 = __shfl(myev, j2);
        u[t] = ((const us4*)(EVB + (size_t)v1 * 256))[lane];
        f[t] = (j2 < cnt) ? 1.f : 0.f;
      }
#pragma unroll
      for (int t = 0; t < 8; t++) {
        acc.x += f[t] * bf2f(u[t].x);
        acc.y += f[t] * bf2f(u[t].y);
        acc.z += f[t] * bf2f(u[t].z);
        acc.w += f[t] * bf2f(u[t].w);
      }
    }
  } else {
    for (int j = s; j < e; j++) {
      int ev = EVo[j];
      us4 u = ((const us4*)(EVB + (size_t)ev * 256))[lane];
      acc.x += bf2f(u.x); acc.y += bf2f(u.y);
      acc.z += bf2f(u.z); acc.w += bf2f(u.w);
    }
  }
  us4 u = {f2bf(acc.x), f2bf(acc.y), f2bf(acc.z), f2bf(acc.w)};
  ((us4*)(outb + (size_t)o * 256))[lane] = u;
}

// ---------------- driver ----------------

extern "C" void kernel_launch(void* const* d_in, const int* in_sizes, int n_in,
                              void* d_out, int out_size, void* d_ws, size_t ws_size,
                              hipStream_t stream) {
  (void)n_in; (void)out_size;
  const float* object_X = (const float*)d_in[0];
  const float* event_X = (const float*)d_in[1];
  const float* Wo = (const float*)d_in[2];   const float* bo = (const float*)d_in[3];
  const float* go = (const float*)d_in[4];   const float* bon = (const float*)d_in[5];
  const float* We = (const float*)d_in[6];   const float* be = (const float*)d_in[7];
  const float* ge = (const float*)d_in[8];   const float* ben = (const float*)d_in[9];
  const float* Wu = (const float*)d_in[10];  const float* bu = (const float*)d_in[11];
  const float* Wl = (const float*)d_in[12];  const float* bl = (const float*)d_in[13];
  const float* g1 = (const float*)d_in[14];  const float* b1 = (const float*)d_in[15];
  const float* g2 = (const float*)d_in[16];  const float* b2 = (const float*)d_in[17];
  const float* Wh1 = (const float*)d_in[18]; const float* ah1 = (const float*)d_in[19];
  const float* Wh2 = (const float*)d_in[20]; const float* ah2 = (const float*)d_in[21];
  const int* oe_ev = (const int*)d_in[22];
  const int* oe_obj = (const int*)d_in[23];
  const int* hg_node = (const int*)d_in[24];
  const int* hg_edge = (const int*)d_in[25];

  const int N_OBJ = in_sizes[0] / 256;
  const int N_EV = in_sizes[1] / 256;
  const int E1 = in_sizes[22];
  const int E2 = in_sizes[24];
  const int NN = N_EV + N_OBJ;
  const int MEV = ((N_EV + 63) / 64) * 64;
  const int MOB = ((N_OBJ + 63) / 64) * 64;
  const int MX = ((NN + 63) / 64) * 64;
  const int EMX = E2 > E1 ? E2 : E1;

  char* p = (char*)d_ws;
  auto take = [&](size_t bytes) {
    char* r = p;
    p += (bytes + 255) & ~(size_t)255;
    return r;
  };
  unsigned short* WF = (unsigned short*)take((size_t)6 * 65536 * 2);  // 0.79 MB frag-packed
  unsigned short* XBF = (unsigned short*)take((size_t)MX * 256 * 2);  // 76.8 MB  X / XW / h
  unsigned short* SB = (unsigned short*)take((size_t)MOB * 256 * 2);  // 51.2 MB staging
  unsigned short* EF = SB;  // alias (bf16): SB dead once the obj2 GEMM has consumed it
  float* S1 = (float*)take((size_t)NN * 4);
  float* S2 = (float*)take((size_t)N_EV * 4);
  int* NS = (int*)take((size_t)(NN + 1) * 4);      // node CSR starts
  int* ES = (int*)take((size_t)(N_EV + 1) * 4);    // edge CSR starts
  int* OS = (int*)take((size_t)(N_OBJ + 1) * 4);   // obj CSR starts
  int* CNTn = (int*)take((size_t)NN * 4);          // counts, reused as fill cursors
  int* CNTe = (int*)take((size_t)N_EV * 4);
  int* CNTo = (int*)take((size_t)N_OBJ * 4);
  int2* PEn = (int2*)take((size_t)E2 * 8);         // (e0, hg_edge[e0]) in node-CSR order
  int* NDe = (int*)take((size_t)E2 * 4);           // hg_node values in edge-CSR order
  int* EVo = (int*)take((size_t)E1 * 4);           // oe_ev values in obj-CSR order
  size_t need = (size_t)(p - (char*)d_ws);
  if (need > ws_size)
    fprintf(stderr, "[kernel_launch] WS OVERFLOW: need=%zu have=%zu\n", need, ws_size);

  float* out = (float*)d_out;
  // obj skip (bf16, 51.2 MB) lives in d_out — dead region until layer-2 outputs
  unsigned short* OBJB = (unsigned short*)d_out;

  // --- weights -> bf16 fragment-packed (one fused launch; slots: We,Wo,Wu,Wl,Wh1,Wh2) ---
  k_pack_w6<<<6 * 256, 256, 0, stream>>>(We, Wo, Wu, Wl, Wh1, Wh2, WF);

  if (MX > NN)
    hipMemsetAsync(XBF + (size_t)NN * 256, 0, (size_t)(MX - NN) * 512, stream);

  // --- CSR builds (node/E2, edge/E2, obj/E1), fused ---
  size_t cnt_span = (size_t)((char*)PEn - (char*)CNTn);  // CNTn..CNTo contiguous
  hipMemsetAsync(CNTn, 0, cnt_span, stream);
  k_count3<<<(EMX + 255) / 256, 256, 0, stream>>>(hg_node, hg_edge, oe_obj, CNTn, CNTe, CNTo,
                                                  E2, E1);
  k_scan3<<<3, 1024, 0, stream>>>(CNTn, NS, NN, CNTe, ES, N_EV, CNTo, OS, N_OBJ);
  hipMemsetAsync(CNTn, 0, cnt_span, stream);
  k_fill3<<<(EMX + 255) / 256, 256, 0, stream>>>(hg_node, hg_edge, oe_ev, oe_obj, NS, ES, OS,
                                                 CNTn, CNTe, CNTo, PEn, NDe, EVo, E2, E1);

  // --- ev = LN(lrelu(event_X@We + be)) -> XBF rows [0,N_EV) bf16 (f32 A fused) ---
  k_gemm_ln<0, 1><<<256, 1024, 0, stream>>>(event_X, WF + 0 * 65536, be, ge, ben, nullptr,
                                            XBF, N_EV, MEV / 16);
  // --- obj = LN(lrelu(object_X@Wo + bo)) -> OBJB bf16 (in d_out) ---
  k_gemm_ln<0, 1><<<256, 1024, 0, stream>>>(object_X, WF + 1 * 65536, bo, go, bon, nullptr,
                                            OBJB, N_OBJ, MOB / 16);
  // --- msg (CSR gather, bf16) -> SB; obj1 = LN(lrelu(msg@Wu+bu)+obj) -> SB ---
  k_obj_gather<<<(N_OBJ + 3) / 4, 256, 0, stream>>>(XBF, OS, EVo, SB, N_OBJ);
  k_gemm_ln<1, 0><<<256, 1024, 0, stream>>>(SB, WF + 2 * 65536, bu, g1, b1, OBJB, SB, N_OBJ,
                                            MOB / 16);
  // --- obj2 = LN(lrelu(obj1@Wl+bl)+obj1) -> XBF rows [N_EV,NN) bf16 ---
  k_gemm_ln<1, 0><<<256, 1024, 0, stream>>>(SB, WF + 3 * 65536, bl, g2, b2, SB,
                                            XBF + (size_t)N_EV * 256, N_OBJ, MOB / 16);

  // --- HGNN layer 1: h -> XBF bf16 (SB now dead; EF aliases it) ---
  k_gemm_xw<<<256, 1024, 0, stream>>>(XBF, WF + 4 * 65536, ah1, S1, NN, MX / 16);
  k_edge_gather<<<(N_EV + 3) / 4, 256, 0, stream>>>(XBF, ES, NDe, ah1 + 256, EF, S2, N_EV);
  k_node_gather<0><<<(NN + 3) / 4, 256, 0, stream>>>(NS, PEn, S1, S2, EF, XBF, nullptr,
                                                     nullptr, NN);
  // --- HGNN layer 2: h f32 + attn -> d_out ---
  k_gemm_xw<<<256, 1024, 0, stream>>>(XBF, WF + 5 * 65536, ah2, S1, NN, MX / 16);
  k_edge_gather<<<(N_EV + 3) / 4, 256, 0, stream>>>(XBF, ES, NDe, ah2 + 256, EF, S2, N_EV);
  k_node_gather<1><<<(NN + 3) / 4, 256, 0, stream>>>(NS, PEn, S1, S2, EF, nullptr, out,
                                                     out + (size_t)NN * 256, NN);
}

// Round 8
// 1206.133 us; speedup vs baseline: 3.0043x; 3.0020x over previous
//
#include <hip/hip_runtime.h>
#include <cstdio>

typedef __attribute__((ext_vector_type(8))) short short8_t;
typedef __attribute__((ext_vector_type(8))) unsigned short ushort8_t;
typedef __attribute__((ext_vector_type(4))) unsigned short us4;
typedef __attribute__((ext_vector_type(4))) float f32x4;

__device__ __forceinline__ unsigned short f2bf(float f) {
  unsigned u = __float_as_uint(f);
  u = u + 0x7FFFu + ((u >> 16) & 1u);
  return (unsigned short)(u >> 16);
}
__device__ __forceinline__ float bf2f(unsigned short h) {
  return __uint_as_float((unsigned)h << 16);
}
__device__ __forceinline__ float lrelu(float x) { return x > 0.f ? x : 0.2f * x; }

// ---------------- weight pack ----------------
// Pack all 6 weights into MFMA-fragment order. The GEMM reads B fragments straight
// from L2 (128 KB/matrix, always resident): lane reads 16B at
// WF[ ((nt*8+ks)*64 + lane)*8 ], perfectly coalesced. Element W[k][n]:
//   col n -> nt = n>>4, l16 = n&15 ; k -> ks = k>>5, quad = (k>>3)&3, j = k&7
__global__ void k_pack_w6(const float* __restrict__ W0, const float* __restrict__ W1,
                          const float* __restrict__ W2, const float* __restrict__ W3,
                          const float* __restrict__ W4, const float* __restrict__ W5,
                          unsigned short* __restrict__ WF) {
  int which = blockIdx.x >> 8, k = blockIdx.x & 255, n = threadIdx.x;
  const float* W = which == 0 ? W0 : which == 1 ? W1 : which == 2 ? W2
                 : which == 3 ? W3 : which == 4 ? W4 : W5;
  int nt = n >> 4, l16 = n & 15;
  int ks = k >> 5, quad = (k >> 3) & 3, j = k & 7;
  size_t idx = ((size_t)which << 16) + (size_t)(((nt * 8 + ks) * 64 + quad * 16 + l16) * 8 + j);
  WF[idx] = f2bf(W[k * 256 + n]);
}

// ---------------- CSR build (fused over the 3 index arrays) ----------------

__global__ void k_count3(const int* __restrict__ hg_node, const int* __restrict__ hg_edge,
                         const int* __restrict__ oe_obj, int* __restrict__ cn,
                         int* __restrict__ ce, int* __restrict__ co, int nE2, int nE1) {
  int e = blockIdx.x * blockDim.x + threadIdx.x;
  if (e < nE2) {
    atomicAdd(&cn[hg_node[e]], 1);
    atomicAdd(&ce[hg_edge[e]], 1);
  }
  if (e < nE1) atomicAdd(&co[oe_obj[e]], 1);
}

// fill CSR-ordered VALUE arrays directly (kills the perm->index hop in gathers):
//   PE[node pos]  = (e0, hg_edge[e0])  (int2, one 8B scatter)
//   NDe[edge pos] = hg_node[e]
//   EVo[obj pos]  = oe_ev[e]
__global__ void k_fill3(const int* __restrict__ hg_node, const int* __restrict__ hg_edge,
                        const int* __restrict__ oe_ev, const int* __restrict__ oe_obj,
                        const int* __restrict__ NS, const int* __restrict__ ES,
                        const int* __restrict__ OS, int* __restrict__ curn,
                        int* __restrict__ cure, int* __restrict__ curo,
                        int2* __restrict__ PE, int* __restrict__ NDe, int* __restrict__ EVo,
                        int nE2, int nE1) {
  int e = blockIdx.x * blockDim.x + threadIdx.x;
  if (e < nE2) {
    int sn = hg_node[e], se = hg_edge[e];
    int pn = NS[sn] + atomicAdd(&curn[sn], 1);
    PE[pn] = make_int2(e, se);
    int pe = ES[se] + atomicAdd(&cure[se], 1);
    NDe[pe] = sn;
  }
  if (e < nE1) {
    int so = oe_obj[e];
    int po = OS[so] + atomicAdd(&curo[so], 1);
    EVo[po] = oe_ev[e];
  }
}

// three single-block exclusive scans running concurrently (block b -> job b).
// starts[0..n] (starts[n] = total). block = 1024.
__global__ __launch_bounds__(1024) void k_scan3(const int* __restrict__ c0, int* __restrict__ s0,
                                                int n0, const int* __restrict__ c1,
                                                int* __restrict__ s1, int n1,
                                                const int* __restrict__ c2, int* __restrict__ s2,
                                                int n2) {
  const int* cnt;
  int* starts;
  int n;
  if (blockIdx.x == 0) { cnt = c0; starts = s0; n = n0; }
  else if (blockIdx.x == 1) { cnt = c1; starts = s1; n = n1; }
  else { cnt = c2; starts = s2; n = n2; }
  __shared__ int wsum[16];
  int tid = threadIdx.x, lane = tid & 63, w = tid >> 6;
  int carry = 0;
  for (int base = 0; base < n; base += 4096) {
    int i0 = base + tid * 4;
    int4 c = make_int4(0, 0, 0, 0);
    if (i0 + 3 < n) c = *(const int4*)(cnt + i0);
    else {
      if (i0 < n) c.x = cnt[i0];
      if (i0 + 1 < n) c.y = cnt[i0 + 1];
      if (i0 + 2 < n) c.z = cnt[i0 + 2];
      if (i0 + 3 < n) c.w = cnt[i0 + 3];
    }
    int tsum = c.x + c.y + c.z + c.w;
    int inc = tsum;
    for (int o = 1; o < 64; o <<= 1) {
      int v = __shfl_up(inc, o);
      if (lane >= o) inc += v;
    }
    if (lane == 63) wsum[w] = inc;
    __syncthreads();
    int woff = 0;
    for (int k = 0; k < w; k++) woff += wsum[k];
    int excl = carry + woff + inc - tsum;
    if (i0 < n) starts[i0] = excl;
    if (i0 + 1 < n) starts[i0 + 1] = excl + c.x;
    if (i0 + 2 < n) starts[i0 + 2] = excl + c.x + c.y;
    if (i0 + 3 < n) starts[i0 + 3] = excl + c.x + c.y + c.z;
    int total = 0;
    for (int k = 0; k < 16; k++) total += wsum[k];
    carry += total;
    __syncthreads();
  }
  if (tid == 0) starts[n] = carry;
}

// ---------------- column-split GEMM (+bias+lrelu+skip+LN), B read from L2 -------------
// Spill-proof by construction: 4 waves share one 16-row tile, each wave owns 64 cols
// (4 nt). Live set: acc 4xf32x4 (16 VGPR) + af[8] (32) + temps ~ 60 < 64, so the
// allocator's default 64-VGPR target cannot spill (rounds 4-7: full-row-per-wave
// needed 64-reg acc -> scratch spill -> 1.28 GB HBM/dispatch; two allocator-control
// attributes were ignored). B fragments come straight from L2-resident WF (128 KB).
// LN's 256-col stats cross the 4 waves via a 1 KB double-buffered LDS array +
// one __syncthreads per tile.
template <int HAS_SKIP, int A_F32>
__global__ __launch_bounds__(256) void k_gemm_ln(const void* __restrict__ Av,
                                                 const unsigned short* __restrict__ WF,
                                                 const float* __restrict__ bias,
                                                 const float* __restrict__ gamma,
                                                 const float* __restrict__ beta,
                                                 const unsigned short* skip,
                                                 unsigned short* outb, int rows, int nTiles) {
  __shared__ float red[2][4][16][2];  // [buf][wave][row][s|q]
  int tid = threadIdx.x;
  int wave = tid >> 6, lane = tid & 63;
  int quad = lane >> 4, l16 = lane & 15;
  int buf = 0;
  for (int t = blockIdx.x; t < nTiles; t += gridDim.x, buf ^= 1) {
    size_t row0 = (size_t)t * 16;
    size_t arow = row0 + l16;
    short8_t af[8];
    if (A_F32) {
      bool inr = arow < (size_t)rows;
      const float4* ap = (const float4*)((const float*)Av + arow * 256);
#pragma unroll
      for (int ks = 0; ks < 8; ks++) {
        float4 f0 = make_float4(0.f, 0.f, 0.f, 0.f), f1 = f0;
        if (inr) {
          f0 = ap[ks * 8 + quad * 2];
          f1 = ap[ks * 8 + quad * 2 + 1];
        }
        ushort8_t a;
        a[0] = f2bf(f0.x); a[1] = f2bf(f0.y); a[2] = f2bf(f0.z); a[3] = f2bf(f0.w);
        a[4] = f2bf(f1.x); a[5] = f2bf(f1.y); a[6] = f2bf(f1.z); a[7] = f2bf(f1.w);
        af[ks] = (short8_t)a;
      }
    } else {
      const ushort8_t* ap = (const ushort8_t*)((const unsigned short*)Av + arow * 256);
#pragma unroll
      for (int ks = 0; ks < 8; ks++) af[ks] = (short8_t)ap[ks * 4 + quad];
    }

    f32x4 acc[4];
#pragma unroll
    for (int i = 0; i < 4; i++) acc[i] = (f32x4){0.f, 0.f, 0.f, 0.f};
#pragma unroll
    for (int ks = 0; ks < 8; ks++) {
#pragma unroll
      for (int c = 0; c < 4; c++) {
        int nt = wave * 4 + c;
        short8_t bf = *(const short8_t*)&WF[(size_t)(((nt * 8 + ks) * 64 + lane) * 8)];
        acc[c] = __builtin_amdgcn_mfma_f32_16x16x32_bf16(af[ks], bf, acc[c], 0, 0, 0);
      }
    }

    size_t rbase = row0 + quad * 4;
    float s[4] = {0, 0, 0, 0}, q[4] = {0, 0, 0, 0};
#pragma unroll
    for (int c = 0; c < 4; c++) {
      int col = (wave * 4 + c) * 16 + l16;
      float bv = bias[col];
#pragma unroll
      for (int r = 0; r < 4; r++) {
        float x = lrelu(acc[c][r] + bv);
        if (HAS_SKIP) {
          if (rbase + r < (size_t)rows) x += bf2f(skip[(rbase + r) * 256 + col]);
        }
        acc[c][r] = x;
        s[r] += x;
        q[r] += x * x;
      }
    }
#pragma unroll
    for (int o = 1; o < 16; o <<= 1)
#pragma unroll
      for (int r = 0; r < 4; r++) {
        s[r] += __shfl_xor(s[r], o);
        q[r] += __shfl_xor(q[r], o);
      }
    if (l16 == 0) {
#pragma unroll
      for (int r = 0; r < 4; r++) {
        red[buf][wave][quad * 4 + r][0] = s[r];
        red[buf][wave][quad * 4 + r][1] = q[r];
      }
    }
    __syncthreads();
    float mr[4], rs[4];
#pragma unroll
    for (int r = 0; r < 4; r++) {
      int row = quad * 4 + r;
      float S = red[buf][0][row][0] + red[buf][1][row][0] + red[buf][2][row][0] +
                red[buf][3][row][0];
      float Q = red[buf][0][row][1] + red[buf][1][row][1] + red[buf][2][row][1] +
                red[buf][3][row][1];
      float m = S * (1.f / 256.f);
      float v = Q * (1.f / 256.f) - m * m;
      mr[r] = m;
      rs[r] = rsqrtf(v + 1e-5f);
    }
#pragma unroll
    for (int c = 0; c < 4; c++) {
      int col = (wave * 4 + c) * 16 + l16;
      float g = gamma[col], bb = beta[col];
#pragma unroll
      for (int r = 0; r < 4; r++) {
        if (rbase + r < (size_t)rows) {
          float y = (acc[c][r] - mr[r]) * rs[r] * g + bb;
          outb[(rbase + r) * 256 + col] = f2bf(y);
        }
      }
    }
  }
}

// ---------------- column-split GEMM for HGNN: XW (bf16, in-place) + s1 = XW@a1 --------
// Same structure. The reduction barrier doubles as the fence between the af reads and
// the in-place A writes (all waves' reads precede it).
__global__ __launch_bounds__(256) void k_gemm_xw(unsigned short* A,
                                                 const unsigned short* __restrict__ WF,
                                                 const float* __restrict__ a1,
                                                 float* __restrict__ s1, int rows,
                                                 int nTiles) {
  __shared__ float red[2][4][16];
  int tid = threadIdx.x;
  int wave = tid >> 6, lane = tid & 63;
  int quad = lane >> 4, l16 = lane & 15;
  int buf = 0;
  for (int t = blockIdx.x; t < nTiles; t += gridDim.x, buf ^= 1) {
    size_t row0 = (size_t)t * 16;
    size_t arow = row0 + l16;
    short8_t af[8];
    const ushort8_t* ap = (const ushort8_t*)(A + arow * 256);
#pragma unroll
    for (int ks = 0; ks < 8; ks++) af[ks] = (short8_t)ap[ks * 4 + quad];

    f32x4 acc[4];
#pragma unroll
    for (int i = 0; i < 4; i++) acc[i] = (f32x4){0.f, 0.f, 0.f, 0.f};
#pragma unroll
    for (int ks = 0; ks < 8; ks++) {
#pragma unroll
      for (int c = 0; c < 4; c++) {
        int nt = wave * 4 + c;
        short8_t bf = *(const short8_t*)&WF[(size_t)(((nt * 8 + ks) * 64 + lane) * 8)];
        acc[c] = __builtin_amdgcn_mfma_f32_16x16x32_bf16(af[ks], bf, acc[c], 0, 0, 0);
      }
    }

    size_t rbase = row0 + quad * 4;
    float s[4] = {0, 0, 0, 0};
#pragma unroll
    for (int c = 0; c < 4; c++) {
      float av = a1[(wave * 4 + c) * 16 + l16];
#pragma unroll
      for (int r = 0; r < 4; r++) s[r] += acc[c][r] * av;
    }
#pragma unroll
    for (int o = 1; o < 16; o <<= 1)
#pragma unroll
      for (int r = 0; r < 4; r++) s[r] += __shfl_xor(s[r], o);
    if (l16 == 0) {
#pragma unroll
      for (int r = 0; r < 4; r++) red[buf][wave][quad * 4 + r] = s[r];
    }
    __syncthreads();  // partials visible; also fences af reads vs in-place writes
#pragma unroll
    for (int c = 0; c < 4; c++) {
      int col = (wave * 4 + c) * 16 + l16;
#pragma unroll
      for (int r = 0; r < 4; r++)
        if (rbase + r < (size_t)rows) A[(rbase + r) * 256 + col] = f2bf(acc[c][r]);
    }
    if (wave == 0 && l16 == 0) {
#pragma unroll
      for (int r = 0; r < 4; r++) {
        int row = quad * 4 + r;
        if (rbase + r < (size_t)rows) {
          s1[rbase + r] = red[buf][0][row] + red[buf][1][row] + red[buf][2][row] +
                          red[buf][3][row];
        }
      }
    }
  }
}

// ---------------- CSR gathers ----------------
// Pass 1 loads CSR-ordered metadata lane-parallel (single hop). Accumulate pass
// broadcasts via __shfl and issues row loads in batches of 8 (MLP). EF is stored
// bf16 (halves the dominant random-row stream); s2 stays computed from the f32
// accumulator so attention weights are bit-identical to the f32-EF version.

// per hyperedge r (one wave): ef[r] = mean of XW[node] rows (bf16 out); s2[r] = ef_f32·a2
__global__ __launch_bounds__(256) void k_edge_gather(const unsigned short* __restrict__ XW,
                                                     const int* __restrict__ ES,
                                                     const int* __restrict__ NDe,
                                                     const float* __restrict__ a2,
                                                     unsigned short* __restrict__ EF,
                                                     float* __restrict__ s2, int nEdges) {
  int wave = threadIdx.x >> 6, lane = threadIdx.x & 63;
  int r = blockIdx.x * 4 + wave;
  if (r >= nEdges) return;
  int s = ES[r], e = ES[r + 1];
  int cnt = e - s;
  float4 acc = make_float4(0.f, 0.f, 0.f, 0.f);
  if (cnt <= 64) {
    int myn = 0;
    if (lane < cnt) myn = NDe[s + lane];
    for (int base = 0; base < cnt; base += 8) {
      us4 u[8];
      float f[8];
#pragma unroll
      for (int t = 0; t < 8; t++) {
        int j2 = base + t;  // <= 63 always (cnt <= 64)
        int n1 = __shfl(myn, j2);
        u[t] = ((const us4*)(XW + (size_t)n1 * 256))[lane];
        f[t] = (j2 < cnt) ? 1.f : 0.f;
      }
#pragma unroll
      for (int t = 0; t < 8; t++) {
        acc.x += f[t] * bf2f(u[t].x);
        acc.y += f[t] * bf2f(u[t].y);
        acc.z += f[t] * bf2f(u[t].z);
        acc.w += f[t] * bf2f(u[t].w);
      }
    }
  } else {
    for (int j = s; j < e; j++) {
      int n = NDe[j];
      us4 u = ((const us4*)(XW + (size_t)n * 256))[lane];
      acc.x += bf2f(u.x); acc.y += bf2f(u.y);
      acc.z += bf2f(u.z); acc.w += bf2f(u.w);
    }
  }
  float inv = 1.f / (float)(cnt > 1 ? cnt : 1);
  acc.x *= inv; acc.y *= inv; acc.z *= inv; acc.w *= inv;
  us4 ub = {f2bf(acc.x), f2bf(acc.y), f2bf(acc.z), f2bf(acc.w)};
  ((us4*)(EF + (size_t)r * 256))[lane] = ub;
  float4 a = ((const float4*)a2)[lane];
  float d = acc.x * a.x + acc.y * a.y + acc.z * a.z + acc.w * a.w;
  for (int o = 32; o; o >>= 1) d += __shfl_xor(d, o);
  if (lane == 0) s2[r] = d;
}

// per node n (one wave): in-wave softmax over incidences + weighted EF gather + lrelu
template <int WRITE_ATTN>
__global__ __launch_bounds__(256) void k_node_gather(const int* __restrict__ NS,
                                                     const int2* __restrict__ PE,
                                                     const float* __restrict__ s1,
                                                     const float* __restrict__ s2,
                                                     const unsigned short* __restrict__ EF,
                                                     unsigned short* outb, float* outf,
                                                     float* attn_out, int nNodes) {
  int wave = threadIdx.x >> 6, lane = threadIdx.x & 63;
  int n = blockIdx.x * 4 + wave;
  if (n >= nNodes) return;
  int s = NS[n], e = NS[n + 1];
  int cnt = e - s;
  float s1n = s1[n];
  float4 acc = make_float4(0.f, 0.f, 0.f, 0.f);
  if (cnt <= 64) {
    int mye0 = 0, myed = 0;
    float myscore = -3.4e38f;
    bool act = lane < cnt;
    if (act) {
      int2 pe = PE[s + lane];
      mye0 = pe.x;
      myed = pe.y;
      myscore = lrelu(s1n + s2[myed]);
    }
    float mymax = myscore;
    for (int o = 32; o; o >>= 1) mymax = fmaxf(mymax, __shfl_xor(mymax, o));
    float myexp = act ? __expf(myscore - mymax) : 0.f;
    float mysum = myexp;
    for (int o = 32; o; o >>= 1) mysum += __shfl_xor(mysum, o);
    float zinv = 1.f / fmaxf(mysum, 1e-9f);
    float myw = myexp * zinv;  // == 0 for inactive lanes
    if (WRITE_ATTN && act) attn_out[mye0] = myw;
    for (int base = 0; base < cnt; base += 8) {
      us4 v[8];
      float w[8];
#pragma unroll
      for (int t = 0; t < 8; t++) {
        int j2 = base + t;  // <= 63 always
        int ed = __shfl(myed, j2);
        w[t] = __shfl(myw, j2);
        v[t] = ((const us4*)(EF + (size_t)ed * 256))[lane];
      }
#pragma unroll
      for (int t = 0; t < 8; t++) {
        acc.x += w[t] * bf2f(v[t].x);
        acc.y += w[t] * bf2f(v[t].y);
        acc.z += w[t] * bf2f(v[t].z);
        acc.w += w[t] * bf2f(v[t].w);
      }
    }
  } else {
    float mymax = -3.4e38f;
    for (int j = s + lane; j < e; j += 64) {
      mymax = fmaxf(mymax, lrelu(s1n + s2[PE[j].y]));
    }
    for (int o = 32; o; o >>= 1) mymax = fmaxf(mymax, __shfl_xor(mymax, o));
    float mysum = 0.f;
    for (int j = s + lane; j < e; j += 64) {
      mysum += __expf(lrelu(s1n + s2[PE[j].y]) - mymax);
    }
    for (int o = 32; o; o >>= 1) mysum += __shfl_xor(mysum, o);
    float zinv = 1.f / fmaxf(mysum, 1e-9f);
    for (int j = s; j < e; j++) {
      int2 pe = PE[j];
      float w = __expf(lrelu(s1n + s2[pe.y]) - mymax) * zinv;
      if (WRITE_ATTN) {
        if (lane == 0) attn_out[pe.x] = w;
      }
      us4 v = ((const us4*)(EF + (size_t)pe.y * 256))[lane];
      acc.x += w * bf2f(v.x); acc.y += w * bf2f(v.y);
      acc.z += w * bf2f(v.z); acc.w += w * bf2f(v.w);
    }
  }
  acc.x = lrelu(acc.x); acc.y = lrelu(acc.y);
  acc.z = lrelu(acc.z); acc.w = lrelu(acc.w);
  if (outb) {
    us4 u = {f2bf(acc.x), f2bf(acc.y), f2bf(acc.z), f2bf(acc.w)};
    ((us4*)(outb + (size_t)n * 256))[lane] = u;
  } else {
    ((float4*)(outf + (size_t)n * 256))[lane] = acc;
  }
}

// per object o (one wave): msg[o] = sum of ev rows (bf16 in, bf16 out)
__global__ __launch_bounds__(256) void k_obj_gather(const unsigned short* __restrict__ EVB,
                                                    const int* __restrict__ OS,
                                                    const int* __restrict__ EVo,
                                                    unsigned short* __restrict__ outb,
                                                    int nObj) {
  int wave = threadIdx.x >> 6, lane = threadIdx.x & 63;
  int o = blockIdx.x * 4 + wave;
  if (o >= nObj) return;
  int s = OS[o], e = OS[o + 1];
  int cnt = e - s;
  float4 acc = make_float4(0.f, 0.f, 0.f, 0.f);
  if (cnt <= 64) {
    int myev = 0;
    if (lane < cnt) myev = EVo[s + lane];
    for (int base = 0; base < cnt; base += 8) {
      us4 u[8];
      float f[8];
#pragma unroll
      for (int t = 0; t < 8; t++) {
        int j2 = base + t;  // <= 63 always
        int v1 = __shfl(myev, j2);
        u[t] = ((const us4*)(EVB + (size_t)v1 * 256))[lane];
        f[t] = (j2 < cnt) ? 1.f : 0.f;
      }
#pragma unroll
      for (int t = 0; t < 8; t++) {
        acc.x += f[t] * bf2f(u[t].x);
        acc.y += f[t] * bf2f(u[t].y);
        acc.z += f[t] * bf2f(u[t].z);
        acc.w += f[t] * bf2f(u[t].w);
      }
    }
  } else {
    for (int j = s; j < e; j++) {
      int ev = EVo[j];
      us4 u = ((const us4*)(EVB + (size_t)ev * 256))[lane];
      acc.x += bf2f(u.x); acc.y += bf2f(u.y);
      acc.z += bf2f(u.z); acc.w += bf2f(u.w);
    }
  }
  us4 u = {f2bf(acc.x), f2bf(acc.y), f2bf(acc.z), f2bf(acc.w)};
  ((us4*)(outb + (size_t)o * 256))[lane] = u;
}

// ---------------- driver ----------------

extern "C" void kernel_launch(void* const* d_in, const int* in_sizes, int n_in,
                              void* d_out, int out_size, void* d_ws, size_t ws_size,
                              hipStream_t stream) {
  (void)n_in; (void)out_size;
  const float* object_X = (const float*)d_in[0];
  const float* event_X = (const float*)d_in[1];
  const float* Wo = (const float*)d_in[2];   const float* bo = (const float*)d_in[3];
  const float* go = (const float*)d_in[4];   const float* bon = (const float*)d_in[5];
  const float* We = (const float*)d_in[6];   const float* be = (const float*)d_in[7];
  const float* ge = (const float*)d_in[8];   const float* ben = (const float*)d_in[9];
  const float* Wu = (const float*)d_in[10];  const float* bu = (const float*)d_in[11];
  const float* Wl = (const float*)d_in[12];  const float* bl = (const float*)d_in[13];
  const float* g1 = (const float*)d_in[14];  const float* b1 = (const float*)d_in[15];
  const float* g2 = (const float*)d_in[16];  const float* b2 = (const float*)d_in[17];
  const float* Wh1 = (const float*)d_in[18]; const float* ah1 = (const float*)d_in[19];
  const float* Wh2 = (const float*)d_in[20]; const float* ah2 = (const float*)d_in[21];
  const int* oe_ev = (const int*)d_in[22];
  const int* oe_obj = (const int*)d_in[23];
  const int* hg_node = (const int*)d_in[24];
  const int* hg_edge = (const int*)d_in[25];

  const int N_OBJ = in_sizes[0] / 256;
  const int N_EV = in_sizes[1] / 256;
  const int E1 = in_sizes[22];
  const int E2 = in_sizes[24];
  const int NN = N_EV + N_OBJ;
  const int MEV = ((N_EV + 63) / 64) * 64;
  const int MOB = ((N_OBJ + 63) / 64) * 64;
  const int MX = ((NN + 63) / 64) * 64;
  const int EMX = E2 > E1 ? E2 : E1;
  const int TEV = MEV / 16, TOB = MOB / 16, TX = MX / 16;
  auto gsz = [](int t) { return t < 2048 ? t : 2048; };

  char* p = (char*)d_ws;
  auto take = [&](size_t bytes) {
    char* r = p;
    p += (bytes + 255) & ~(size_t)255;
    return r;
  };
  unsigned short* WF = (unsigned short*)take((size_t)6 * 65536 * 2);  // 0.79 MB frag-packed
  unsigned short* XBF = (unsigned short*)take((size_t)MX * 256 * 2);  // 76.8 MB  X / XW / h
  unsigned short* SB = (unsigned short*)take((size_t)MOB * 256 * 2);  // 51.2 MB staging
  unsigned short* EF = SB;  // alias (bf16): SB dead once the obj2 GEMM has consumed it
  float* S1 = (float*)take((size_t)NN * 4);
  float* S2 = (float*)take((size_t)N_EV * 4);
  int* NS = (int*)take((size_t)(NN + 1) * 4);      // node CSR starts
  int* ES = (int*)take((size_t)(N_EV + 1) * 4);    // edge CSR starts
  int* OS = (int*)take((size_t)(N_OBJ + 1) * 4);   // obj CSR starts
  int* CNTn = (int*)take((size_t)NN * 4);          // counts, reused as fill cursors
  int* CNTe = (int*)take((size_t)N_EV * 4);
  int* CNTo = (int*)take((size_t)N_OBJ * 4);
  int2* PEn = (int2*)take((size_t)E2 * 8);         // (e0, hg_edge[e0]) in node-CSR order
  int* NDe = (int*)take((size_t)E2 * 4);           // hg_node values in edge-CSR order
  int* EVo = (int*)take((size_t)E1 * 4);           // oe_ev values in obj-CSR order
  size_t need = (size_t)(p - (char*)d_ws);
  if (need > ws_size)
    fprintf(stderr, "[kernel_launch] WS OVERFLOW: need=%zu have=%zu\n", need, ws_size);

  float* out = (float*)d_out;
  // obj skip (bf16, 51.2 MB) lives in d_out — dead region until layer-2 outputs
  unsigned short* OBJB = (unsigned short*)d_out;

  // --- weights -> bf16 fragment-packed (one fused launch; slots: We,Wo,Wu,Wl,Wh1,Wh2) ---
  k_pack_w6<<<6 * 256, 256, 0, stream>>>(We, Wo, Wu, Wl, Wh1, Wh2, WF);

  if (MX > NN)
    hipMemsetAsync(XBF + (size_t)NN * 256, 0, (size_t)(MX - NN) * 512, stream);

  // --- CSR builds (node/E2, edge/E2, obj/E1), fused ---
  size_t cnt_span = (size_t)((char*)PEn - (char*)CNTn);  // CNTn..CNTo contiguous
  hipMemsetAsync(CNTn, 0, cnt_span, stream);
  k_count3<<<(EMX + 255) / 256, 256, 0, stream>>>(hg_node, hg_edge, oe_obj, CNTn, CNTe, CNTo,
                                                  E2, E1);
  k_scan3<<<3, 1024, 0, stream>>>(CNTn, NS, NN, CNTe, ES, N_EV, CNTo, OS, N_OBJ);
  hipMemsetAsync(CNTn, 0, cnt_span, stream);
  k_fill3<<<(EMX + 255) / 256, 256, 0, stream>>>(hg_node, hg_edge, oe_ev, oe_obj, NS, ES, OS,
                                                 CNTn, CNTe, CNTo, PEn, NDe, EVo, E2, E1);

  // --- ev = LN(lrelu(event_X@We + be)) -> XBF rows [0,N_EV) bf16 (f32 A fused) ---
  k_gemm_ln<0, 1><<<gsz(TEV), 256, 0, stream>>>(event_X, WF + 0 * 65536, be, ge, ben, nullptr,
                                                XBF, N_EV, TEV);
  // --- obj = LN(lrelu(object_X@Wo + bo)) -> OBJB bf16 (in d_out) ---
  k_gemm_ln<0, 1><<<gsz(TOB), 256, 0, stream>>>(object_X, WF + 1 * 65536, bo, go, bon, nullptr,
                                                OBJB, N_OBJ, TOB);
  // --- msg (CSR gather, bf16) -> SB; obj1 = LN(lrelu(msg@Wu+bu)+obj) -> SB ---
  k_obj_gather<<<(N_OBJ + 3) / 4, 256, 0, stream>>>(XBF, OS, EVo, SB, N_OBJ);
  k_gemm_ln<1, 0><<<gsz(TOB), 256, 0, stream>>>(SB, WF + 2 * 65536, bu, g1, b1, OBJB, SB,
                                                N_OBJ, TOB);
  // --- obj2 = LN(lrelu(obj1@Wl+bl)+obj1) -> XBF rows [N_EV,NN) bf16 ---
  k_gemm_ln<1, 0><<<gsz(TOB), 256, 0, stream>>>(SB, WF + 3 * 65536, bl, g2, b2, SB,
                                                XBF + (size_t)N_EV * 256, N_OBJ, TOB);

  // --- HGNN layer 1: h -> XBF bf16 (SB now dead; EF aliases it) ---
  k_gemm_xw<<<gsz(TX), 256, 0, stream>>>(XBF, WF + 4 * 65536, ah1, S1, NN, TX);
  k_edge_gather<<<(N_EV + 3) / 4, 256, 0, stream>>>(XBF, ES, NDe, ah1 + 256, EF, S2, N_EV);
  k_node_gather<0><<<(NN + 3) / 4, 256, 0, stream>>>(NS, PEn, S1, S2, EF, XBF, nullptr,
                                                     nullptr, NN);
  // --- HGNN layer 2: h f32 + attn -> d_out ---
  k_gemm_xw<<<gsz(TX), 256, 0, stream>>>(XBF, WF + 5 * 65536, ah2, S1, NN, TX);
  k_edge_gather<<<(N_EV + 3) / 4, 256, 0, stream>>>(XBF, ES, NDe, ah2 + 256, EF, S2, N_EV);
  k_node_gather<1><<<(NN + 3) / 4, 256, 0, stream>>>(NS, PEn, S1, S2, EF, nullptr, out,
                                                     out + (size_t)NN * 256, NN);
}

// Round 9
// 1148.000 us; speedup vs baseline: 3.1564x; 1.0506x over previous
//
#include <hip/hip_runtime.h>
#include <cstdio>

typedef __attribute__((ext_vector_type(8))) short short8_t;
typedef __attribute__((ext_vector_type(8))) unsigned short ushort8_t;
typedef __attribute__((ext_vector_type(4))) unsigned short us4;
typedef __attribute__((ext_vector_type(4))) float f32x4;

__device__ __forceinline__ unsigned short f2bf(float f) {
  unsigned u = __float_as_uint(f);
  u = u + 0x7FFFu + ((u >> 16) & 1u);
  return (unsigned short)(u >> 16);
}
__device__ __forceinline__ float bf2f(unsigned short h) {
  return __uint_as_float((unsigned)h << 16);
}
__device__ __forceinline__ float lrelu(float x) { return x > 0.f ? x : 0.2f * x; }

// ---------------- weight pack ----------------
// Pack all 6 weights into MFMA-fragment order. The GEMM reads B fragments straight
// from L2 (128 KB/matrix, always resident): lane reads 16B at
// WF[ ((nt*8+ks)*64 + lane)*8 ], perfectly coalesced. Element W[k][n]:
//   col n -> nt = n>>4, l16 = n&15 ; k -> ks = k>>5, quad = (k>>3)&3, j = k&7
__global__ void k_pack_w6(const float* __restrict__ W0, const float* __restrict__ W1,
                          const float* __restrict__ W2, const float* __restrict__ W3,
                          const float* __restrict__ W4, const float* __restrict__ W5,
                          unsigned short* __restrict__ WF) {
  int which = blockIdx.x >> 8, k = blockIdx.x & 255, n = threadIdx.x;
  const float* W = which == 0 ? W0 : which == 1 ? W1 : which == 2 ? W2
                 : which == 3 ? W3 : which == 4 ? W4 : W5;
  int nt = n >> 4, l16 = n & 15;
  int ks = k >> 5, quad = (k >> 3) & 3, j = k & 7;
  size_t idx = ((size_t)which << 16) + (size_t)(((nt * 8 + ks) * 64 + quad * 16 + l16) * 8 + j);
  WF[idx] = f2bf(W[k * 256 + n]);
}

// ---------------- CSR build bodies (rank-trick: atomics ONLY in count) ----------------
// count: rk[e] = atomicAdd(&cnt[key],1) -- the rank within the segment.
// fill:  pos = starts[key] + rk[e]      -- pure scatter, no atomics, no cursors.

__device__ __forceinline__ void count_body(int b, const int* __restrict__ hg_node,
                                           const int* __restrict__ hg_edge,
                                           const int* __restrict__ oe_obj,
                                           int* __restrict__ cn, int* __restrict__ ce,
                                           int* __restrict__ co, int* __restrict__ rkn,
                                           int* __restrict__ rke, int* __restrict__ rko,
                                           int nE2, int nE1) {
  int e = b * 256 + (int)threadIdx.x;
  if (e < nE2) {
    rkn[e] = atomicAdd(&cn[hg_node[e]], 1);
    rke[e] = atomicAdd(&ce[hg_edge[e]], 1);
  }
  if (e < nE1) rko[e] = atomicAdd(&co[oe_obj[e]], 1);
}

__device__ __forceinline__ void fill_body(int b, const int* __restrict__ hg_node,
                                          const int* __restrict__ hg_edge,
                                          const int* __restrict__ oe_ev,
                                          const int* __restrict__ oe_obj,
                                          const int* __restrict__ NS,
                                          const int* __restrict__ ES,
                                          const int* __restrict__ OS,
                                          const int* __restrict__ rkn,
                                          const int* __restrict__ rke,
                                          const int* __restrict__ rko,
                                          int2* __restrict__ PE, int* __restrict__ NDe,
                                          int* __restrict__ EVo, int nE2, int nE1) {
  int e = b * 256 + (int)threadIdx.x;
  if (e < nE2) {
    int sn = hg_node[e], se = hg_edge[e];
    PE[NS[sn] + rkn[e]] = make_int2(e, se);
    NDe[ES[se] + rke[e]] = sn;
  }
  if (e < nE1) EVo[OS[oe_obj[e]] + rko[e]] = oe_ev[e];
}

// three single-block exclusive scans running concurrently (block b -> job b).
// starts[0..n] (starts[n] = total). block = 1024.
__global__ __launch_bounds__(1024) void k_scan3(const int* __restrict__ c0, int* __restrict__ s0,
                                                int n0, const int* __restrict__ c1,
                                                int* __restrict__ s1, int n1,
                                                const int* __restrict__ c2, int* __restrict__ s2,
                                                int n2) {
  const int* cnt;
  int* starts;
  int n;
  if (blockIdx.x == 0) { cnt = c0; starts = s0; n = n0; }
  else if (blockIdx.x == 1) { cnt = c1; starts = s1; n = n1; }
  else { cnt = c2; starts = s2; n = n2; }
  __shared__ int wsum[16];
  int tid = threadIdx.x, lane = tid & 63, w = tid >> 6;
  int carry = 0;
  for (int base = 0; base < n; base += 4096) {
    int i0 = base + tid * 4;
    int4 c = make_int4(0, 0, 0, 0);
    if (i0 + 3 < n) c = *(const int4*)(cnt + i0);
    else {
      if (i0 < n) c.x = cnt[i0];
      if (i0 + 1 < n) c.y = cnt[i0 + 1];
      if (i0 + 2 < n) c.z = cnt[i0 + 2];
      if (i0 + 3 < n) c.w = cnt[i0 + 3];
    }
    int tsum = c.x + c.y + c.z + c.w;
    int inc = tsum;
    for (int o = 1; o < 64; o <<= 1) {
      int v = __shfl_up(inc, o);
      if (lane >= o) inc += v;
    }
    if (lane == 63) wsum[w] = inc;
    __syncthreads();
    int woff = 0;
    for (int k = 0; k < w; k++) woff += wsum[k];
    int excl = carry + woff + inc - tsum;
    if (i0 < n) starts[i0] = excl;
    if (i0 + 1 < n) starts[i0 + 1] = excl + c.x;
    if (i0 + 2 < n) starts[i0 + 2] = excl + c.x + c.y;
    if (i0 + 3 < n) starts[i0 + 3] = excl + c.x + c.y + c.z;
    int total = 0;
    for (int k = 0; k < 16; k++) total += wsum[k];
    carry += total;
    __syncthreads();
  }
  if (tid == 0) starts[n] = carry;
}

// ---------------- column-split GEMM body (+bias+lrelu+skip+LN), B read from L2 --------
// Spill-proof by construction: 4 waves share one 16-row tile, each wave owns 64 cols
// (4 nt). Live set: acc 4xf32x4 (16 VGPR) + af[8] (32) + temps ~ 60 < 64, so the
// allocator's default 64-VGPR target cannot spill. B fragments come straight from
// L2-resident WF (128 KB). LN's 256-col stats cross the 4 waves via a 1 KB
// double-buffered LDS array + one __syncthreads per tile. bid/G passed explicitly so
// the body can be embedded in role-fused launches.
template <int HAS_SKIP, int A_F32>
__device__ __forceinline__ void gemm_ln_body(int bid, int G, const void* __restrict__ Av,
                                             const unsigned short* __restrict__ WF,
                                             const float* __restrict__ bias,
                                             const float* __restrict__ gamma,
                                             const float* __restrict__ beta,
                                             const unsigned short* skip,
                                             unsigned short* outb, int rows, int nTiles) {
  __shared__ float red[2][4][16][2];  // [buf][wave][row][s|q]
  int tid = threadIdx.x;
  int wave = tid >> 6, lane = tid & 63;
  int quad = lane >> 4, l16 = lane & 15;
  int buf = 0;
  for (int t = bid; t < nTiles; t += G, buf ^= 1) {
    size_t row0 = (size_t)t * 16;
    size_t arow = row0 + l16;
    short8_t af[8];
    if (A_F32) {
      bool inr = arow < (size_t)rows;
      const float4* ap = (const float4*)((const float*)Av + arow * 256);
#pragma unroll
      for (int ks = 0; ks < 8; ks++) {
        float4 f0 = make_float4(0.f, 0.f, 0.f, 0.f), f1 = f0;
        if (inr) {
          f0 = ap[ks * 8 + quad * 2];
          f1 = ap[ks * 8 + quad * 2 + 1];
        }
        ushort8_t a;
        a[0] = f2bf(f0.x); a[1] = f2bf(f0.y); a[2] = f2bf(f0.z); a[3] = f2bf(f0.w);
        a[4] = f2bf(f1.x); a[5] = f2bf(f1.y); a[6] = f2bf(f1.z); a[7] = f2bf(f1.w);
        af[ks] = (short8_t)a;
      }
    } else {
      const ushort8_t* ap = (const ushort8_t*)((const unsigned short*)Av + arow * 256);
#pragma unroll
      for (int ks = 0; ks < 8; ks++) af[ks] = (short8_t)ap[ks * 4 + quad];
    }

    f32x4 acc[4];
#pragma unroll
    for (int i = 0; i < 4; i++) acc[i] = (f32x4){0.f, 0.f, 0.f, 0.f};
#pragma unroll
    for (int ks = 0; ks < 8; ks++) {
#pragma unroll
      for (int c = 0; c < 4; c++) {
        int nt = wave * 4 + c;
        short8_t bf = *(const short8_t*)&WF[(size_t)(((nt * 8 + ks) * 64 + lane) * 8)];
        acc[c] = __builtin_amdgcn_mfma_f32_16x16x32_bf16(af[ks], bf, acc[c], 0, 0, 0);
      }
    }

    size_t rbase = row0 + quad * 4;
    float s[4] = {0, 0, 0, 0}, q[4] = {0, 0, 0, 0};
#pragma unroll
    for (int c = 0; c < 4; c++) {
      int col = (wave * 4 + c) * 16 + l16;
      float bv = bias[col];
#pragma unroll
      for (int r = 0; r < 4; r++) {
        float x = lrelu(acc[c][r] + bv);
        if (HAS_SKIP) {
          if (rbase + r < (size_t)rows) x += bf2f(skip[(rbase + r) * 256 + col]);
        }
        acc[c][r] = x;
        s[r] += x;
        q[r] += x * x;
      }
    }
#pragma unroll
    for (int o = 1; o < 16; o <<= 1)
#pragma unroll
      for (int r = 0; r < 4; r++) {
        s[r] += __shfl_xor(s[r], o);
        q[r] += __shfl_xor(q[r], o);
      }
    if (l16 == 0) {
#pragma unroll
      for (int r = 0; r < 4; r++) {
        red[buf][wave][quad * 4 + r][0] = s[r];
        red[buf][wave][quad * 4 + r][1] = q[r];
      }
    }
    __syncthreads();
    float mr[4], rs[4];
#pragma unroll
    for (int r = 0; r < 4; r++) {
      int row = quad * 4 + r;
      float S = red[buf][0][row][0] + red[buf][1][row][0] + red[buf][2][row][0] +
                red[buf][3][row][0];
      float Q = red[buf][0][row][1] + red[buf][1][row][1] + red[buf][2][row][1] +
                red[buf][3][row][1];
      float m = S * (1.f / 256.f);
      float v = Q * (1.f / 256.f) - m * m;
      mr[r] = m;
      rs[r] = rsqrtf(v + 1e-5f);
    }
#pragma unroll
    for (int c = 0; c < 4; c++) {
      int col = (wave * 4 + c) * 16 + l16;
      float g = gamma[col], bb = beta[col];
#pragma unroll
      for (int r = 0; r < 4; r++) {
        if (rbase + r < (size_t)rows) {
          float y = (acc[c][r] - mr[r]) * rs[r] * g + bb;
          outb[(rbase + r) * 256 + col] = f2bf(y);
        }
      }
    }
  }
}

// plain GEMM+LN (obj1/obj2, with skip)
template <int HAS_SKIP, int A_F32>
__global__ __launch_bounds__(256) void k_gemm_ln(const void* __restrict__ Av,
                                                 const unsigned short* __restrict__ WF,
                                                 const float* __restrict__ bias,
                                                 const float* __restrict__ gamma,
                                                 const float* __restrict__ beta,
                                                 const unsigned short* skip,
                                                 unsigned short* outb, int rows, int nTiles) {
  gemm_ln_body<HAS_SKIP, A_F32>(blockIdx.x, gridDim.x, Av, WF, bias, gamma, beta, skip,
                                outb, rows, nTiles);
}

// fused: blocks [0,CB) run count (retire fast, GEMM blocks backfill); [CB,CB+G) run GEMM.
__global__ __launch_bounds__(256) void k_gemm_count(
    const void* __restrict__ Av, const unsigned short* __restrict__ WF,
    const float* __restrict__ bias, const float* __restrict__ gamma,
    const float* __restrict__ beta, unsigned short* outb, int rows, int nTiles, int CB,
    int G, const int* __restrict__ hg_node, const int* __restrict__ hg_edge,
    const int* __restrict__ oe_obj, int* cn, int* ce, int* co, int* rkn, int* rke, int* rko,
    int nE2, int nE1) {
  int b = blockIdx.x;
  if (b < CB)
    count_body(b, hg_node, hg_edge, oe_obj, cn, ce, co, rkn, rke, rko, nE2, nE1);
  else
    gemm_ln_body<0, 1>(b - CB, G, Av, WF, bias, gamma, beta, nullptr, outb, rows, nTiles);
}

__global__ __launch_bounds__(256) void k_gemm_fill(
    const void* __restrict__ Av, const unsigned short* __restrict__ WF,
    const float* __restrict__ bias, const float* __restrict__ gamma,
    const float* __restrict__ beta, unsigned short* outb, int rows, int nTiles, int CB,
    int G, const int* __restrict__ hg_node, const int* __restrict__ hg_edge,
    const int* __restrict__ oe_ev, const int* __restrict__ oe_obj,
    const int* __restrict__ NS, const int* __restrict__ ES, const int* __restrict__ OS,
    const int* __restrict__ rkn, const int* __restrict__ rke, const int* __restrict__ rko,
    int2* PE, int* NDe, int* EVo, int nE2, int nE1) {
  int b = blockIdx.x;
  if (b < CB)
    fill_body(b, hg_node, hg_edge, oe_ev, oe_obj, NS, ES, OS, rkn, rke, rko, PE, NDe, EVo,
              nE2, nE1);
  else
    gemm_ln_body<0, 1>(b - CB, G, Av, WF, bias, gamma, beta, nullptr, outb, rows, nTiles);
}

// ---------------- column-split GEMM for HGNN: XW (bf16, in-place) + s1 = XW@a1 --------
// Same structure. The reduction barrier doubles as the fence between the af reads and
// the in-place A writes (all waves' reads precede it).
__global__ __launch_bounds__(256) void k_gemm_xw(unsigned short* A,
                                                 const unsigned short* __restrict__ WF,
                                                 const float* __restrict__ a1,
                                                 float* __restrict__ s1, int rows,
                                                 int nTiles) {
  __shared__ float red[2][4][16];
  int tid = threadIdx.x;
  int wave = tid >> 6, lane = tid & 63;
  int quad = lane >> 4, l16 = lane & 15;
  int buf = 0;
  for (int t = blockIdx.x; t < nTiles; t += gridDim.x, buf ^= 1) {
    size_t row0 = (size_t)t * 16;
    size_t arow = row0 + l16;
    short8_t af[8];
    const ushort8_t* ap = (const ushort8_t*)(A + arow * 256);
#pragma unroll
    for (int ks = 0; ks < 8; ks++) af[ks] = (short8_t)ap[ks * 4 + quad];

    f32x4 acc[4];
#pragma unroll
    for (int i = 0; i < 4; i++) acc[i] = (f32x4){0.f, 0.f, 0.f, 0.f};
#pragma unroll
    for (int ks = 0; ks < 8; ks++) {
#pragma unroll
      for (int c = 0; c < 4; c++) {
        int nt = wave * 4 + c;
        short8_t bf = *(const short8_t*)&WF[(size_t)(((nt * 8 + ks) * 64 + lane) * 8)];
        acc[c] = __builtin_amdgcn_mfma_f32_16x16x32_bf16(af[ks], bf, acc[c], 0, 0, 0);
      }
    }

    size_t rbase = row0 + quad * 4;
    float s[4] = {0, 0, 0, 0};
#pragma unroll
    for (int c = 0; c < 4; c++) {
      float av = a1[(wave * 4 + c) * 16 + l16];
#pragma unroll
      for (int r = 0; r < 4; r++) s[r] += acc[c][r] * av;
    }
#pragma unroll
    for (int o = 1; o < 16; o <<= 1)
#pragma unroll
      for (int r = 0; r < 4; r++) s[r] += __shfl_xor(s[r], o);
    if (l16 == 0) {
#pragma unroll
      for (int r = 0; r < 4; r++) red[buf][wave][quad * 4 + r] = s[r];
    }
    __syncthreads();  // partials visible; also fences af reads vs in-place writes
#pragma unroll
    for (int c = 0; c < 4; c++) {
      int col = (wave * 4 + c) * 16 + l16;
#pragma unroll
      for (int r = 0; r < 4; r++)
        if (rbase + r < (size_t)rows) A[(rbase + r) * 256 + col] = f2bf(acc[c][r]);
    }
    if (wave == 0 && l16 == 0) {
#pragma unroll
      for (int r = 0; r < 4; r++) {
        int row = quad * 4 + r;
        if (rbase + r < (size_t)rows) {
          s1[rbase + r] = red[buf][0][row] + red[buf][1][row] + red[buf][2][row] +
                          red[buf][3][row];
        }
      }
    }
  }
}

// ---------------- CSR gathers ----------------
// Pass 1 loads CSR-ordered metadata lane-parallel (single hop). Accumulate pass
// broadcasts via __shfl and issues row loads in batches of 8 (MLP). EF is stored
// bf16 (halves the dominant random-row stream); s2 stays computed from the f32
// accumulator so attention weights are bit-identical to the f32-EF version.

// per hyperedge r (one wave): ef[r] = mean of XW[node] rows (bf16 out); s2[r] = ef_f32·a2
__global__ __launch_bounds__(256) void k_edge_gather(const unsigned short* __restrict__ XW,
                                                     const int* __restrict__ ES,
                                                     const int* __restrict__ NDe,
                                                     const float* __restrict__ a2,
                                                     unsigned short* __restrict__ EF,
                                                     float* __restrict__ s2, int nEdges) {
  int wave = threadIdx.x >> 6, lane = threadIdx.x & 63;
  int r = blockIdx.x * 4 + wave;
  if (r >= nEdges) return;
  int s = ES[r], e = ES[r + 1];
  int cnt = e - s;
  float4 acc = make_float4(0.f, 0.f, 0.f, 0.f);
  if (cnt <= 64) {
    int myn = 0;
    if (lane < cnt) myn = NDe[s + lane];
    for (int base = 0; base < cnt; base += 8) {
      us4 u[8];
      float f[8];
#pragma unroll
      for (int t = 0; t < 8; t++) {
        int j2 = base + t;  // <= 63 always (cnt <= 64)
        int n1 = __shfl(myn, j2);
        u[t] = ((const us4*)(XW + (size_t)n1 * 256))[lane];
        f[t] = (j2 < cnt) ? 1.f : 0.f;
      }
#pragma unroll
      for (int t = 0; t < 8; t++) {
        acc.x += f[t] * bf2f(u[t].x);
        acc.y += f[t] * bf2f(u[t].y);
        acc.z += f[t] * bf2f(u[t].z);
        acc.w += f[t] * bf2f(u[t].w);
      }
    }
  } else {
    for (int j = s; j < e; j++) {
      int n = NDe[j];
      us4 u = ((const us4*)(XW + (size_t)n * 256))[lane];
      acc.x += bf2f(u.x); acc.y += bf2f(u.y);
      acc.z += bf2f(u.z); acc.w += bf2f(u.w);
    }
  }
  float inv = 1.f / (float)(cnt > 1 ? cnt : 1);
  acc.x *= inv; acc.y *= inv; acc.z *= inv; acc.w *= inv;
  us4 ub = {f2bf(acc.x), f2bf(acc.y), f2bf(acc.z), f2bf(acc.w)};
  ((us4*)(EF + (size_t)r * 256))[lane] = ub;
  float4 a = ((const float4*)a2)[lane];
  float d = acc.x * a.x + acc.y * a.y + acc.z * a.z + acc.w * a.w;
  for (int o = 32; o; o >>= 1) d += __shfl_xor(d, o);
  if (lane == 0) s2[r] = d;
}

// per node n (one wave): in-wave softmax over incidences + weighted EF gather + lrelu
template <int WRITE_ATTN>
__global__ __launch_bounds__(256) void k_node_gather(const int* __restrict__ NS,
                                                     const int2* __restrict__ PE,
                                                     const float* __restrict__ s1,
                                                     const float* __restrict__ s2,
                                                     const unsigned short* __restrict__ EF,
                                                     unsigned short* outb, float* outf,
                                                     float* attn_out, int nNodes) {
  int wave = threadIdx.x >> 6, lane = threadIdx.x & 63;
  int n = blockIdx.x * 4 + wave;
  if (n >= nNodes) return;
  int s = NS[n], e = NS[n + 1];
  int cnt = e - s;
  float s1n = s1[n];
  float4 acc = make_float4(0.f, 0.f, 0.f, 0.f);
  if (cnt <= 64) {
    int mye0 = 0, myed = 0;
    float myscore = -3.4e38f;
    bool act = lane < cnt;
    if (act) {
      int2 pe = PE[s + lane];
      mye0 = pe.x;
      myed = pe.y;
      myscore = lrelu(s1n + s2[myed]);
    }
    float mymax = myscore;
    for (int o = 32; o; o >>= 1) mymax = fmaxf(mymax, __shfl_xor(mymax, o));
    float myexp = act ? __expf(myscore - mymax) : 0.f;
    float mysum = myexp;
    for (int o = 32; o; o >>= 1) mysum += __shfl_xor(mysum, o);
    float zinv = 1.f / fmaxf(mysum, 1e-9f);
    float myw = myexp * zinv;  // == 0 for inactive lanes
    if (WRITE_ATTN && act) attn_out[mye0] = myw;
    for (int base = 0; base < cnt; base += 8) {
      us4 v[8];
      float w[8];
#pragma unroll
      for (int t = 0; t < 8; t++) {
        int j2 = base + t;  // <= 63 always
        int ed = __shfl(myed, j2);
        w[t] = __shfl(myw, j2);
        v[t] = ((const us4*)(EF + (size_t)ed * 256))[lane];
      }
#pragma unroll
      for (int t = 0; t < 8; t++) {
        acc.x += w[t] * bf2f(v[t].x);
        acc.y += w[t] * bf2f(v[t].y);
        acc.z += w[t] * bf2f(v[t].z);
        acc.w += w[t] * bf2f(v[t].w);
      }
    }
  } else {
    float mymax = -3.4e38f;
    for (int j = s + lane; j < e; j += 64) {
      mymax = fmaxf(mymax, lrelu(s1n + s2[PE[j].y]));
    }
    for (int o = 32; o; o >>= 1) mymax = fmaxf(mymax, __shfl_xor(mymax, o));
    float mysum = 0.f;
    for (int j = s + lane; j < e; j += 64) {
      mysum += __expf(lrelu(s1n + s2[PE[j].y]) - mymax);
    }
    for (int o = 32; o; o >>= 1) mysum += __shfl_xor(mysum, o);
    float zinv = 1.f / fmaxf(mysum, 1e-9f);
    for (int j = s; j < e; j++) {
      int2 pe = PE[j];
      float w = __expf(lrelu(s1n + s2[pe.y]) - mymax) * zinv;
      if (WRITE_ATTN) {
        if (lane == 0) attn_out[pe.x] = w;
      }
      us4 v = ((const us4*)(EF + (size_t)pe.y * 256))[lane];
      acc.x += w * bf2f(v.x); acc.y += w * bf2f(v.y);
      acc.z += w * bf2f(v.z); acc.w += w * bf2f(v.w);
    }
  }
  acc.x = lrelu(acc.x); acc.y = lrelu(acc.y);
  acc.z = lrelu(acc.z); acc.w = lrelu(acc.w);
  if (outb) {
    us4 u = {f2bf(acc.x), f2bf(acc.y), f2bf(acc.z), f2bf(acc.w)};
    ((us4*)(outb + (size_t)n * 256))[lane] = u;
  } else {
    ((float4*)(outf + (size_t)n * 256))[lane] = acc;
  }
}

// per object o (one wave): msg[o] = sum of ev rows (bf16 in, bf16 out)
__global__ __launch_bounds__(256) void k_obj_gather(const unsigned short* __restrict__ EVB,
                                                    const int* __restrict__ OS,
                                                    const int* __restrict__ EVo,
                                                    unsigned short* __restrict__ outb,
                                                    int nObj) {
  int wave = threadIdx.x >> 6, lane = threadIdx.x & 63;
  int o = blockIdx.x * 4 + wave;
  if (o >= nObj) return;
  int s = OS[o], e = OS[o + 1];
  int cnt = e - s;
  float4 acc = make_float4(0.f, 0.f, 0.f, 0.f);
  if (cnt <= 64) {
    int myev = 0;
    if (lane < cnt) myev = EVo[s + lane];
    for (int base = 0; base < cnt; base += 8) {
      us4 u[8];
      float f[8];
#pragma unroll
      for (int t = 0; t < 8; t++) {
        int j2 = base + t;  // <= 63 always
        int v1 = __shfl(myev, j2);
        u[t] = ((const us4*)(EVB + (size_t)v1 * 256))[lane];
        f[t] = (j2 < cnt) ? 1.f : 0.f;
      }
#pragma unroll
      for (int t = 0; t < 8; t++) {
        acc.x += f[t] * bf2f(u[t].x);
        acc.y += f[t] * bf2f(u[t].y);
        acc.z += f[t] * bf2f(u[t].z);
        acc.w += f[t] * bf2f(u[t].w);
      }
    }
  } else {
    for (int j = s; j < e; j++) {
      int ev = EVo[j];
      us4 u = ((const us4*)(EVB + (size_t)ev * 256))[lane];
      acc.x += bf2f(u.x); acc.y += bf2f(u.y);
      acc.z += bf2f(u.z); acc.w += bf2f(u.w);
    }
  }
  us4 u = {f2bf(acc.x), f2bf(acc.y), f2bf(acc.z), f2bf(acc.w)};
  ((us4*)(outb + (size_t)o * 256))[lane] = u;
}

// ---------------- driver ----------------

extern "C" void kernel_launch(void* const* d_in, const int* in_sizes, int n_in,
                              void* d_out, int out_size, void* d_ws, size_t ws_size,
                              hipStream_t stream) {
  (void)n_in; (void)out_size;
  const float* object_X = (const float*)d_in[0];
  const float* event_X = (const float*)d_in[1];
  const float* Wo = (const float*)d_in[2];   const float* bo = (const float*)d_in[3];
  const float* go = (const float*)d_in[4];   const float* bon = (const float*)d_in[5];
  const float* We = (const float*)d_in[6];   const float* be = (const float*)d_in[7];
  const float* ge = (const float*)d_in[8];   const float* ben = (const float*)d_in[9];
  const float* Wu = (const float*)d_in[10];  const float* bu = (const float*)d_in[11];
  const float* Wl = (const float*)d_in[12];  const float* bl = (const float*)d_in[13];
  const float* g1 = (const float*)d_in[14];  const float* b1 = (const float*)d_in[15];
  const float* g2 = (const float*)d_in[16];  const float* b2 = (const float*)d_in[17];
  const float* Wh1 = (const float*)d_in[18]; const float* ah1 = (const float*)d_in[19];
  const float* Wh2 = (const float*)d_in[20]; const float* ah2 = (const float*)d_in[21];
  const int* oe_ev = (const int*)d_in[22];
  const int* oe_obj = (const int*)d_in[23];
  const int* hg_node = (const int*)d_in[24];
  const int* hg_edge = (const int*)d_in[25];

  const int N_OBJ = in_sizes[0] / 256;
  const int N_EV = in_sizes[1] / 256;
  const int E1 = in_sizes[22];
  const int E2 = in_sizes[24];
  const int NN = N_EV + N_OBJ;
  const int MEV = ((N_EV + 63) / 64) * 64;
  const int MOB = ((N_OBJ + 63) / 64) * 64;
  const int MX = ((NN + 63) / 64) * 64;
  const int EMX = E2 > E1 ? E2 : E1;
  const int TEV = MEV / 16, TOB = MOB / 16, TX = MX / 16;
  auto gsz = [](int t) { return t < 2048 ? t : 2048; };
  const int CB = (EMX + 255) / 256;

  char* p = (char*)d_ws;
  auto take = [&](size_t bytes) {
    char* r = p;
    p += (bytes + 255) & ~(size_t)255;
    return r;
  };
  unsigned short* WF = (unsigned short*)take((size_t)6 * 65536 * 2);  // 0.79 MB frag-packed
  unsigned short* XBF = (unsigned short*)take((size_t)MX * 256 * 2);  // 76.8 MB  X / XW / h
  unsigned short* SB = (unsigned short*)take((size_t)MOB * 256 * 2);  // 51.2 MB staging
  unsigned short* EF = SB;  // alias (bf16): SB dead once the obj2 GEMM has consumed it
  float* S1 = (float*)take((size_t)NN * 4);
  float* S2 = (float*)take((size_t)N_EV * 4);
  int* NS = (int*)take((size_t)(NN + 1) * 4);      // node CSR starts
  int* ES = (int*)take((size_t)(N_EV + 1) * 4);    // edge CSR starts
  int* OS = (int*)take((size_t)(N_OBJ + 1) * 4);   // obj CSR starts
  int* CNTn = (int*)take((size_t)NN * 4);          // counts (zeroed once)
  int* CNTe = (int*)take((size_t)N_EV * 4);
  int* CNTo = (int*)take((size_t)N_OBJ * 4);
  int* RKn = (int*)take((size_t)E2 * 4);           // rank within node segment
  int* RKe = (int*)take((size_t)E2 * 4);           // rank within edge segment
  int* RKo = (int*)take((size_t)E1 * 4);           // rank within obj segment
  int2* PEn = (int2*)take((size_t)E2 * 8);         // (e0, hg_edge[e0]) in node-CSR order
  int* NDe = (int*)take((size_t)E2 * 4);           // hg_node values in edge-CSR order
  int* EVo = (int*)take((size_t)E1 * 4);           // oe_ev values in obj-CSR order
  size_t need = (size_t)(p - (char*)d_ws);
  if (need > ws_size)
    fprintf(stderr, "[kernel_launch] WS OVERFLOW: need=%zu have=%zu\n", need, ws_size);

  float* out = (float*)d_out;
  // obj skip (bf16, 51.2 MB) lives in d_out — dead region until layer-2 outputs
  unsigned short* OBJB = (unsigned short*)d_out;

  // --- weights -> bf16 fragment-packed (one fused launch; slots: We,Wo,Wu,Wl,Wh1,Wh2) ---
  k_pack_w6<<<6 * 256, 256, 0, stream>>>(We, Wo, Wu, Wl, Wh1, Wh2, WF);

  if (MX > NN)
    hipMemsetAsync(XBF + (size_t)NN * 256, 0, (size_t)(MX - NN) * 512, stream);

  // --- CSR counts zeroed once (rank-trick: no cursors, no second memset) ---
  size_t cnt_span = (size_t)((char*)RKn - (char*)CNTn);  // CNTn..CNTo contiguous
  hipMemsetAsync(CNTn, 0, cnt_span, stream);

  // --- ev GEMM ∥ count+rank (count blocks first so they retire and GEMM backfills) ---
  {
    int G = gsz(TEV);
    k_gemm_count<<<CB + G, 256, 0, stream>>>(event_X, WF + 0 * 65536, be, ge, ben, XBF,
                                             N_EV, TEV, CB, G, hg_node, hg_edge, oe_obj,
                                             CNTn, CNTe, CNTo, RKn, RKe, RKo, E2, E1);
  }
  k_scan3<<<3, 1024, 0, stream>>>(CNTn, NS, NN, CNTe, ES, N_EV, CNTo, OS, N_OBJ);
  // --- obj GEMM ∥ fill (atomic-free scatter using ranks) ---
  {
    int G = gsz(TOB);
    k_gemm_fill<<<CB + G, 256, 0, stream>>>(object_X, WF + 1 * 65536, bo, go, bon, OBJB,
                                            N_OBJ, TOB, CB, G, hg_node, hg_edge, oe_ev,
                                            oe_obj, NS, ES, OS, RKn, RKe, RKo, PEn, NDe,
                                            EVo, E2, E1);
  }

  // --- msg (CSR gather, bf16) -> SB; obj1 = LN(lrelu(msg@Wu+bu)+obj) -> SB ---
  k_obj_gather<<<(N_OBJ + 3) / 4, 256, 0, stream>>>(XBF, OS, EVo, SB, N_OBJ);
  k_gemm_ln<1, 0><<<gsz(TOB), 256, 0, stream>>>(SB, WF + 2 * 65536, bu, g1, b1, OBJB, SB,
                                                N_OBJ, TOB);
  // --- obj2 = LN(lrelu(obj1@Wl+bl)+obj1) -> XBF rows [N_EV,NN) bf16 ---
  k_gemm_ln<1, 0><<<gsz(TOB), 256, 0, stream>>>(SB, WF + 3 * 65536, bl, g2, b2, SB,
                                                XBF + (size_t)N_EV * 256, N_OBJ, TOB);

  // --- HGNN layer 1: h -> XBF bf16 (SB now dead; EF aliases it) ---
  k_gemm_xw<<<gsz(TX), 256, 0, stream>>>(XBF, WF + 4 * 65536, ah1, S1, NN, TX);
  k_edge_gather<<<(N_EV + 3) / 4, 256, 0, stream>>>(XBF, ES, NDe, ah1 + 256, EF, S2, N_EV);
  k_node_gather<0><<<(NN + 3) / 4, 256, 0, stream>>>(NS, PEn, S1, S2, EF, XBF, nullptr,
                                                     nullptr, NN);
  // --- HGNN layer 2: h f32 + attn -> d_out ---
  k_gemm_xw<<<gsz(TX), 256, 0, stream>>>(XBF, WF + 5 * 65536, ah2, S1, NN, TX);
  k_edge_gather<<<(N_EV + 3) / 4, 256, 0, stream>>>(XBF, ES, NDe, ah2 + 256, EF, S2, N_EV);
  k_node_gather<1><<<(NN + 3) / 4, 256, 0, stream>>>(NS, PEn, S1, S2, EF, nullptr, out,
                                                     out + (size_t)NN * 256, NN);
}